// Round 21
// baseline (256.032 us; speedup 1.0000x reference)
//
#include <hip/hip_runtime.h>
#include <hip/hip_bf16.h>
#include <math.h>

#define T_TOK 4096
#define D_EMB 768
#define DFF   3072
#define N_EXP 8
#define MAXT  72
#define CNTS  16

typedef __attribute__((ext_vector_type(8))) short bf16x8;
typedef __attribute__((ext_vector_type(4))) float f32x4;

__device__ __forceinline__ short f2bf(float f) {
  union { __hip_bfloat16 b; short s; } u;
  u.b = __float2bfloat16(f);
  return u.s;
}

// tanh-form GELU (validated r9/r14/r16/r17)
__device__ __forceinline__ float gelu_f(float v) {
  float u = 0.7978845608f * v * (1.0f + 0.044715f * v * v);
  float a = fabsf(u);
  float em = __expf(-2.0f * a);
  float th = (1.0f - em) / (1.0f + em);
  th = (u < 0.0f) ? -th : th;
  return 0.5f * v * (1.0f + th);
}

__device__ __forceinline__ int swz(int row) { return (row ^ (row >> 2)) & 3; }

// spin until *f >= tgt. volatile -> ds_read each iter; fence stops compiler
// motion of subsequent LDS reads/writes above the spin (rule 18 analog).
__device__ __forceinline__ void spin_ge(const int* f, int tgt) {
  volatile const int* vf = f;
  while (*vf < tgt) { asm volatile("s_sleep 1"); }
  __builtin_amdgcn_sched_barrier(0);
  asm volatile("" ::: "memory");
}

// ---------------- zero out + counters ----------------
__global__ void zero_init_kernel(float4* __restrict__ out4, int n4, int* __restrict__ cnt) {
  int i = blockIdx.x * blockDim.x + threadIdx.x;
  if (i < N_EXP * CNTS) cnt[i] = 0;
  float4 z; z.x = z.y = z.z = z.w = 0.f;
  for (int j = i; j < n4; j += gridDim.x * blockDim.x) out4[j] = z;
}

// ---------------- weight -> slab transform (r14, validated) ----------------
__global__ __launch_bounds__(256)
void slab_weights(const float* __restrict__ src, short* __restrict__ dst,
                  int Kt, int Nt, int NCT, int NKTall) {
  __shared__ float t32[32][132];
  int ct = blockIdx.x, kt = blockIdx.y, e = blockIdx.z;
  const float* s = src + ((size_t)e * Kt + kt * 32) * Nt + ct * 128;
  int tid = threadIdx.x;
#pragma unroll
  for (int p4 = 0; p4 < 4; p4++) {
    int idx = tid + p4 * 256;
    int kl = idx >> 5, c4 = idx & 31;
    float4 v = *(const float4*)&s[(size_t)kl * Nt + c4 * 4];
    t32[kl][c4 * 4 + 0] = v.x; t32[kl][c4 * 4 + 1] = v.y;
    t32[kl][c4 * 4 + 2] = v.z; t32[kl][c4 * 4 + 3] = v.w;
  }
  __syncthreads();
  short* d = dst + (((size_t)e * NCT + ct) * NKTall + kt) * 4096;
#pragma unroll
  for (int i = 0; i < 2; i++) {
    int seg = tid + i * 256;
    int row = seg >> 2, p = seg & 3;
    int q = p ^ swz(row);
    union { short sv[8]; uint4 u; } o;
#pragma unroll
    for (int j = 0; j < 8; j++) o.sv[j] = f2bf(t32[q * 8 + j][row]);
    *(uint4*)&d[(size_t)seg * 8] = o.u;
  }
}

// ---------------- gate (validated) ----------------
__global__ __launch_bounds__(256)
void gate_kernel(const float* __restrict__ x, const float* __restrict__ gw,
                 int* __restrict__ cnt, int* __restrict__ tok,
                 float* __restrict__ wgt) {
  __shared__ int lcnt[N_EXP];
  __shared__ int gbase[N_EXP];
  __shared__ int le[32];
  __shared__ float lw[32];
  __shared__ int lpos[32];
  int tid = threadIdx.x, lane = tid & 63, wid = tid >> 6;
  if (tid < N_EXP) lcnt[tid] = 0;
  __syncthreads();

#pragma unroll
  for (int i = 0; i < 4; i++) {
    int t = blockIdx.x * 16 + wid * 4 + i;
    float s[N_EXP];
#pragma unroll
    for (int e = 0; e < N_EXP; e++) s[e] = 0.f;
#pragma unroll
    for (int dd = 0; dd < D_EMB / 64; dd++) {
      int d = dd * 64 + lane;
      float xv = x[(size_t)t * D_EMB + d];
#pragma unroll
      for (int e = 0; e < N_EXP; e++) s[e] += xv * gw[d * N_EXP + e];
    }
#pragma unroll
    for (int e = 0; e < N_EXP; e++) {
#pragma unroll
      for (int off = 32; off > 0; off >>= 1) s[e] += __shfl_xor(s[e], off, 64);
    }
    if (lane == 0) {
      int e0 = 0;
#pragma unroll
      for (int e = 1; e < N_EXP; e++) if (s[e] > s[e0]) e0 = e;
      int e1 = -1;
#pragma unroll
      for (int e = 0; e < N_EXP; e++) {
        if (e == e0) continue;
        if (e1 < 0 || s[e] > s[e1]) e1 = e;
      }
      float p1 = __expf(s[e1] - s[e0]);
      float inv = 1.f / (1.f + p1);
      int idx = (wid * 4 + i) * 2;
      le[idx] = e0; lw[idx] = inv;           lpos[idx] = atomicAdd(&lcnt[e0], 1);
      le[idx + 1] = e1; lw[idx + 1] = p1 * inv; lpos[idx + 1] = atomicAdd(&lcnt[e1], 1);
    }
  }
  __syncthreads();
  if (tid < N_EXP) gbase[tid] = atomicAdd(&cnt[tid * CNTS], lcnt[tid]);
  __syncthreads();
  if (tid < 32) {
    int e = le[tid];
    int t = blockIdx.x * 16 + (tid >> 1);
    int p = gbase[e] + lpos[tid];
    tok[e * T_TOK + p] = t;
    wgt[e * T_TOK + p] = lw[tid];
  }
}

// ---------------- plan ----------------
__global__ void plan_kernel(const int* __restrict__ cnt, int* __restrict__ offs,
                            int* __restrict__ tile_e, int* __restrict__ tile_rt,
                            int* __restrict__ ntiles) {
  if (threadIdx.x != 0 || blockIdx.x != 0) return;
  int o = 0, nt = 0;
  for (int e = 0; e < N_EXP; e++) {
    offs[e] = o;
    int tc = (cnt[e * CNTS] + 127) >> 7;
    for (int i = 0; i < tc; i++) { tile_e[nt] = e; tile_rt[nt] = i; nt++; }
    o += cnt[e * CNTS];
  }
  *ntiles = nt;
}

// ---------------- A-slab gather (r14, validated) ----------------
__global__ __launch_bounds__(256)
void gatherA_kernel(const float* __restrict__ x, const int* __restrict__ tok,
                    const int* __restrict__ cnt, const int* __restrict__ offs,
                    const int* __restrict__ tile_e, const int* __restrict__ tile_rt,
                    const int* __restrict__ ntiles, short* __restrict__ aslab) {
  int tile = blockIdx.x, kt = blockIdx.y;
  if (tile >= *ntiles) return;
  int e = tile_e[tile], rt = tile_rt[tile];
  int ne = cnt[e * CNTS];
  int tid = threadIdx.x;
  short* d = aslab + ((size_t)tile * 24 + kt) * 4096;
#pragma unroll
  for (int i = 0; i < 2; i++) {
    int seg = tid + i * 256;
    int row = seg >> 2, p = seg & 3;
    int q = p ^ swz(row);
    int r = rt * 128 + row; if (r >= ne) r = ne - 1;
    int t = tok[e * T_TOK + r];
    const float* src = x + (size_t)t * D_EMB + kt * 32 + q * 8;
    union { short sv[8]; uint4 u; } o;
#pragma unroll
    for (int j = 0; j < 8; j++) o.sv[j] = f2bf(src[j]);
    *(uint4*)&d[(size_t)seg * 8] = o.u;
  }
}

// ---------------- PRODUCER-CONSUMER grouped GEMM ----------------
// 512 threads: waves 0-3 = consumers (r17 compute, 64x64 each), waves 4-7 =
// producers (global->reg->ds_write into a 4-deep LDS ring). NO barriers in the
// K-loop; per-buffer monotonic counters in LDS:
//   producer round r on buf b: spin cons[b]>=4r; write; lgkmcnt(0); lane0 ds_add prod[b]
//   consumer step t (b=t%4, r=t/4): spin prod[b]>=4(r+1); ds_read frags;
//     lgkmcnt(0); lane0 ds_add cons[b]  (free the buffer BEFORE MFMA -> overlap)
// Consumers never wait on vmcnt; producer writes carry compiler-counted vmcnt.
template<int KDIM, int NDIM, int SPLITK, int GRT, int GCT, int EPI>
__global__ __launch_bounds__(512, 4)
void pc_gemm(const short* __restrict__ Aop, const short* __restrict__ Bslab,
             const int* __restrict__ tok, const float* __restrict__ wgt,
             const int* __restrict__ cnt, const int* __restrict__ offs,
             const int* __restrict__ tile_e, const int* __restrict__ tile_rt,
             const int* __restrict__ ntiles,
             short* __restrict__ hout, float* __restrict__ fout) {
  const int COLT = NDIM / 128;
  const int KS = KDIM / SPLITK;
  const int NKT = KS / 32;                 // FC 24, PROJ 48
  const int NKTALL = KDIM / 32;
  const int ASTRIDE = (EPI == 0) ? 4096 : 32;
  const int BPS = GRT * GCT;
  const int NCG = COLT / GCT;
  const int PER_SK = MAXT * COLT;
  static_assert(NKT % 4 == 0 && NKT >= 8, "ring needs NKT%4==0");

  int nwg = gridDim.x, cpx = nwg >> 3;
  int logical = (blockIdx.x & 7) * cpx + (blockIdx.x >> 3);   // bijective XCD swizzle
  int sk = logical / PER_SK;
  int rem = logical % PER_SK;
  int super = rem / BPS, inner = rem % BPS;
  int band = super / NCG, cg = super % NCG;
  int tile = band * GRT + (inner % GRT);
  int ct = cg * GCT + (inner / GRT);
  if (tile >= *ntiles) return;
  int e = tile_e[tile], rt = tile_rt[tile];
  int ne = cnt[e * CNTS];
  int base = offs[e];

  __shared__ __align__(16) short AsR[4][4096];
  __shared__ __align__(16) short BsR[4][4096];
  __shared__ int prodf[4];
  __shared__ int consf[4];

  int tid = threadIdx.x, lane = tid & 63, wid = tid >> 6;
  if (tid < 4) { prodf[tid] = 0; consf[tid] = 0; }
  __syncthreads();   // flags visible to all 8 waves before the loop

  if (wid < 4) {
    // ======================= CONSUMER =======================
    int wr = (wid >> 1) * 64, wc = (wid & 1) * 64;
    int cb = lane >> 4;
    int offa[4], offb[4];
#pragma unroll
    for (int m = 0; m < 4; m++) {
      int row = wr + m * 16 + (lane & 15);
      offa[m] = row * 32 + ((cb ^ swz(row)) * 8);
    }
#pragma unroll
    for (int n = 0; n < 4; n++) {
      int row = wc + n * 16 + (lane & 15);
      offb[n] = row * 32 + ((cb ^ swz(row)) * 8);
    }

    f32x4 acc[4][4];
#pragma unroll
    for (int m = 0; m < 4; m++)
#pragma unroll
      for (int n = 0; n < 4; n++) acc[m][n] = (f32x4){0.f, 0.f, 0.f, 0.f};

#pragma unroll 1
    for (int tg = 0; tg < NKT / 4; ++tg) {
      int tgt = 4 * (tg + 1);
#pragma unroll
      for (int b = 0; b < 4; ++b) {
        spin_ge(&prodf[b], tgt);
        bf16x8 af[4], bv[4];
#pragma unroll
        for (int m = 0; m < 4; m++) af[m] = *(const bf16x8*)&AsR[b][offa[m]];
#pragma unroll
        for (int n = 0; n < 4; n++) bv[n] = *(const bf16x8*)&BsR[b][offb[n]];
        asm volatile("s_waitcnt lgkmcnt(0)" ::: "memory");   // frags in regs
        __builtin_amdgcn_sched_barrier(0);
        if (lane == 0) atomicAdd(&consf[b], 1);              // free buffer early
#pragma unroll
        for (int m = 0; m < 4; m++)
#pragma unroll
          for (int n = 0; n < 4; n++)
            acc[m][n] = __builtin_amdgcn_mfma_f32_16x16x32_bf16(
                af[m], bv[n], acc[m][n], 0, 0, 0);
      }
    }

    // epilogue (r17)
    int colbase = ct * 128 + wc;
#pragma unroll
    for (int m = 0; m < 4; m++) {
#pragma unroll
      for (int j = 0; j < 4; j++) {
        int rloc = rt * 128 + wr + m * 16 + ((lane >> 4) << 2) + j;
        if (rloc < ne) {
          if (EPI == 0) {
            size_t hrow = (size_t)(base + rloc) * NDIM;
#pragma unroll
            for (int n = 0; n < 4; n++)
              hout[hrow + colbase + n * 16 + (lane & 15)] = f2bf(gelu_f(acc[m][n][j]));
          } else {
            int t = tok[e * T_TOK + rloc];
            float w = wgt[e * T_TOK + rloc];
            float* orow = fout + (size_t)t * NDIM + colbase + (lane & 15);
#pragma unroll
            for (int n = 0; n < 4; n++)
              atomicAdd(orow + n * 16, w * acc[m][n][j]);
          }
        }
      }
    }
  } else {
    // ======================= PRODUCER =======================
    int pl = tid - 256;   // 0..255
    const short* ap0;
    const short* ap1;
    if (EPI == 0) {
      ap0 = Aop + (size_t)tile * NKTALL * 4096 + pl * 8;
      ap1 = ap0 + 2048;
    } else {
      {
        int seg = pl;
        int row = seg >> 2, p = seg & 3;
        int q = p ^ swz(row);
        int r = rt * 128 + row; if (r >= ne) r = ne - 1;
        ap0 = Aop + (size_t)(base + r) * KDIM + sk * KS + q * 8;
      }
      {
        int seg = pl + 256;
        int row = seg >> 2, p = seg & 3;
        int q = p ^ swz(row);
        int r = rt * 128 + row; if (r >= ne) r = ne - 1;
        ap1 = Aop + (size_t)(base + r) * KDIM + sk * KS + q * 8;
      }
    }
    const short* bp0 = Bslab + (((size_t)e * COLT + ct) * NKTALL + sk * NKT) * 4096 + pl * 8;
    const short* bp1 = bp0 + 2048;
    int lo0 = pl * 8, lo1 = (pl + 256) * 8;

    f32x4 s0a0, s0a1, s0b0, s0b1;
    f32x4 s1a0, s1a1, s1b0, s1b1;

#define LOADP(A0, A1, B0, B1, KT) do {                                        \
    int kc_ = (KT) < NKT ? (KT) : (NKT - 1);                                  \
    A0 = *(const f32x4*)(ap0 + (size_t)kc_ * ASTRIDE);                        \
    A1 = *(const f32x4*)(ap1 + (size_t)kc_ * ASTRIDE);                        \
    B0 = *(const f32x4*)(bp0 + (size_t)kc_ * 4096);                          \
    B1 = *(const f32x4*)(bp1 + (size_t)kc_ * 4096);                          \
  } while (0)
#define PUTP(A0, A1, B0, B1, B) do {                                          \
    *(f32x4*)&AsR[B][lo0] = A0; *(f32x4*)&AsR[B][lo1] = A1;                   \
    *(f32x4*)&BsR[B][lo0] = B0; *(f32x4*)&BsR[B][lo1] = B1;                   \
    asm volatile("s_waitcnt lgkmcnt(0)" ::: "memory");                        \
    __builtin_amdgcn_sched_barrier(0);                                        \
    if (lane == 0) atomicAdd(&prodf[B], 1);                                   \
  } while (0)

    LOADP(s0a0, s0a1, s0b0, s0b1, 0);
#pragma unroll 1
    for (int tg = 0; tg < NKT / 4; ++tg) {
      int ctgt = 4 * tg;
      LOADP(s1a0, s1a1, s1b0, s1b1, 4 * tg + 1);
      spin_ge(&consf[0], ctgt);
      PUTP(s0a0, s0a1, s0b0, s0b1, 0);
      LOADP(s0a0, s0a1, s0b0, s0b1, 4 * tg + 2);
      spin_ge(&consf[1], ctgt);
      PUTP(s1a0, s1a1, s1b0, s1b1, 1);
      LOADP(s1a0, s1a1, s1b0, s1b1, 4 * tg + 3);
      spin_ge(&consf[2], ctgt);
      PUTP(s0a0, s0a1, s0b0, s0b1, 2);
      LOADP(s0a0, s0a1, s0b0, s0b1, 4 * tg + 4);
      spin_ge(&consf[3], ctgt);
      PUTP(s1a0, s1a1, s1b0, s1b1, 3);
    }
#undef PUTP
#undef LOADP
  }
}

extern "C" void kernel_launch(void* const* d_in, const int* in_sizes, int n_in,
                              void* d_out, int out_size, void* d_ws, size_t ws_size,
                              hipStream_t stream) {
  const float* x   = (const float*)d_in[0];
  const float* gw  = (const float*)d_in[1];
  const float* wfc = (const float*)d_in[2];
  const float* wpj = (const float*)d_in[3];
  float* out = (float*)d_out;

  char* ws = (char*)d_ws;
  const size_t SZ_ASLAB = (size_t)MAXT * 24 * 4096 * 2;        // 14,155,776
  const size_t SZ_BFC   = (size_t)N_EXP * 24 * 24 * 4096 * 2;  // 37,748,736
  const size_t SZ_BPJ   = (size_t)N_EXP * 6 * 96 * 4096 * 2;   // 37,748,736
  const size_t SZ_H     = (size_t)2 * T_TOK * DFF * 2;         // 50,331,648
  short* aslab = (short*)(ws);
  short* bfc   = (short*)(ws + SZ_ASLAB);
  short* bpj   = (short*)(ws + SZ_ASLAB + SZ_BFC);
  short* h     = (short*)(ws + SZ_ASLAB + SZ_BFC + SZ_BPJ);
  char* p2     = ws + SZ_ASLAB + SZ_BFC + SZ_BPJ + SZ_H;
  int*   tok  = (int*)(p2);
  float* wgt  = (float*)(p2 + (size_t)N_EXP * T_TOK * 4);
  char* p3    = p2 + (size_t)N_EXP * T_TOK * 8;
  int*   cnt     = (int*)(p3);
  int*   offs    = (int*)(p3 + 1024);
  int*   tile_e  = (int*)(p3 + 1024 + 64);
  int*   tile_rt = (int*)(p3 + 1024 + 64 + 512);
  int*   ntiles  = (int*)(p3 + 1024 + 64 + 1024);

  int n4 = out_size / 4;
  zero_init_kernel<<<2048, 256, 0, stream>>>((float4*)out, n4, cnt);
  slab_weights<<<dim3(24, 24, N_EXP), 256, 0, stream>>>(wfc, bfc, D_EMB, DFF, 24, 24);
  slab_weights<<<dim3(6, 96, N_EXP), 256, 0, stream>>>(wpj, bpj, DFF, D_EMB, 6, 96);
  gate_kernel<<<T_TOK / 16, 256, 0, stream>>>(x, gw, cnt, tok, wgt);
  plan_kernel<<<1, 1, 0, stream>>>(cnt, offs, tile_e, tile_rt, ntiles);
  gatherA_kernel<<<dim3(MAXT, 24), 256, 0, stream>>>(x, tok, cnt, offs, tile_e, tile_rt, ntiles, aslab);
  // FC: producer-consumer, A=slab. K=768 (NKT=24), N=3072. grid = 1728 (%8==0)
  pc_gemm<D_EMB, DFF, 1, 8, 8, 0><<<MAXT * (DFF / 128), 512, 0, stream>>>(
      aslab, bfc, tok, wgt, cnt, offs, tile_e, tile_rt, ntiles, h, nullptr);
  // PROJ: producer-consumer, A=h rows. K=3072 split 2 (NKT=48), N=768. grid = 864 (%8==0)
  pc_gemm<DFF, D_EMB, 2, 8, 6, 1><<<2 * MAXT * (D_EMB / 128), 512, 0, stream>>>(
      h, bpj, tok, wgt, cnt, offs, tile_e, tile_rt, ntiles, nullptr, out);
}

// Round 22
// 214.761 us; speedup vs baseline: 1.1922x; 1.1922x over previous
//
#include <hip/hip_runtime.h>
#include <hip/hip_bf16.h>
#include <math.h>

#define T_TOK 4096
#define D_EMB 768
#define DFF   3072
#define N_EXP 8
#define MAXT  72
#define CNTS  16

typedef __attribute__((ext_vector_type(8))) short bf16x8;
typedef __attribute__((ext_vector_type(4))) float f32x4;

__device__ __forceinline__ short f2bf(float f) {
  union { __hip_bfloat16 b; short s; } u;
  u.b = __float2bfloat16(f);
  return u.s;
}

// tanh-form GELU (validated r9/r14/r16/r17, absmax unchanged)
__device__ __forceinline__ float gelu_f(float v) {
  float u = 0.7978845608f * v * (1.0f + 0.044715f * v * v);
  float a = fabsf(u);
  float em = __expf(-2.0f * a);
  float th = (1.0f - em) / (1.0f + em);
  th = (u < 0.0f) ? -th : th;
  return 0.5f * v * (1.0f + th);
}

__device__ __forceinline__ int swz(int row) { return (row ^ (row >> 2)) & 3; }

// ---------------- zero out + counters ----------------
__global__ void zero_init_kernel(float4* __restrict__ out4, int n4, int* __restrict__ cnt) {
  int i = blockIdx.x * blockDim.x + threadIdx.x;
  if (i < N_EXP * CNTS) cnt[i] = 0;
  float4 z; z.x = z.y = z.z = z.w = 0.f;
  for (int j = i; j < n4; j += gridDim.x * blockDim.x) out4[j] = z;
}

// ---------------- weight -> slab transform (r14, validated) ----------------
__global__ __launch_bounds__(256)
void slab_weights(const float* __restrict__ src, short* __restrict__ dst,
                  int Kt, int Nt, int NCT, int NKTall) {
  __shared__ float t32[32][132];
  int ct = blockIdx.x, kt = blockIdx.y, e = blockIdx.z;
  const float* s = src + ((size_t)e * Kt + kt * 32) * Nt + ct * 128;
  int tid = threadIdx.x;
#pragma unroll
  for (int p4 = 0; p4 < 4; p4++) {
    int idx = tid + p4 * 256;
    int kl = idx >> 5, c4 = idx & 31;
    float4 v = *(const float4*)&s[(size_t)kl * Nt + c4 * 4];
    t32[kl][c4 * 4 + 0] = v.x; t32[kl][c4 * 4 + 1] = v.y;
    t32[kl][c4 * 4 + 2] = v.z; t32[kl][c4 * 4 + 3] = v.w;
  }
  __syncthreads();
  short* d = dst + (((size_t)e * NCT + ct) * NKTall + kt) * 4096;
#pragma unroll
  for (int i = 0; i < 2; i++) {
    int seg = tid + i * 256;
    int row = seg >> 2, p = seg & 3;
    int q = p ^ swz(row);
    union { short sv[8]; uint4 u; } o;
#pragma unroll
    for (int j = 0; j < 8; j++) o.sv[j] = f2bf(t32[q * 8 + j][row]);
    *(uint4*)&d[(size_t)seg * 8] = o.u;
  }
}

// ---------------- gate (validated) ----------------
__global__ __launch_bounds__(256)
void gate_kernel(const float* __restrict__ x, const float* __restrict__ gw,
                 int* __restrict__ cnt, int* __restrict__ tok,
                 float* __restrict__ wgt) {
  __shared__ int lcnt[N_EXP];
  __shared__ int gbase[N_EXP];
  __shared__ int le[32];
  __shared__ float lw[32];
  __shared__ int lpos[32];
  int tid = threadIdx.x, lane = tid & 63, wid = tid >> 6;
  if (tid < N_EXP) lcnt[tid] = 0;
  __syncthreads();

#pragma unroll
  for (int i = 0; i < 4; i++) {
    int t = blockIdx.x * 16 + wid * 4 + i;
    float s[N_EXP];
#pragma unroll
    for (int e = 0; e < N_EXP; e++) s[e] = 0.f;
#pragma unroll
    for (int dd = 0; dd < D_EMB / 64; dd++) {
      int d = dd * 64 + lane;
      float xv = x[(size_t)t * D_EMB + d];
#pragma unroll
      for (int e = 0; e < N_EXP; e++) s[e] += xv * gw[d * N_EXP + e];
    }
#pragma unroll
    for (int e = 0; e < N_EXP; e++) {
#pragma unroll
      for (int off = 32; off > 0; off >>= 1) s[e] += __shfl_xor(s[e], off, 64);
    }
    if (lane == 0) {
      int e0 = 0;
#pragma unroll
      for (int e = 1; e < N_EXP; e++) if (s[e] > s[e0]) e0 = e;
      int e1 = -1;
#pragma unroll
      for (int e = 0; e < N_EXP; e++) {
        if (e == e0) continue;
        if (e1 < 0 || s[e] > s[e1]) e1 = e;
      }
      float p1 = __expf(s[e1] - s[e0]);
      float inv = 1.f / (1.f + p1);
      int idx = (wid * 4 + i) * 2;
      le[idx] = e0; lw[idx] = inv;           lpos[idx] = atomicAdd(&lcnt[e0], 1);
      le[idx + 1] = e1; lw[idx + 1] = p1 * inv; lpos[idx + 1] = atomicAdd(&lcnt[e1], 1);
    }
  }
  __syncthreads();
  if (tid < N_EXP) gbase[tid] = atomicAdd(&cnt[tid * CNTS], lcnt[tid]);
  __syncthreads();
  if (tid < 32) {
    int e = le[tid];
    int t = blockIdx.x * 16 + (tid >> 1);
    int p = gbase[e] + lpos[tid];
    tok[e * T_TOK + p] = t;
    wgt[e * T_TOK + p] = lw[tid];
  }
}

// ---------------- plan ----------------
__global__ void plan_kernel(const int* __restrict__ cnt, int* __restrict__ offs,
                            int* __restrict__ tile_e, int* __restrict__ tile_rt,
                            int* __restrict__ ntiles) {
  if (threadIdx.x != 0 || blockIdx.x != 0) return;
  int o = 0, nt = 0;
  for (int e = 0; e < N_EXP; e++) {
    offs[e] = o;
    int tc = (cnt[e * CNTS] + 127) >> 7;
    for (int i = 0; i < tc; i++) { tile_e[nt] = e; tile_rt[nt] = i; nt++; }
    o += cnt[e * CNTS];
  }
  *ntiles = nt;
}

// ---------------- A-slab gather (r14, validated) ----------------
__global__ __launch_bounds__(256)
void gatherA_kernel(const float* __restrict__ x, const int* __restrict__ tok,
                    const int* __restrict__ cnt, const int* __restrict__ offs,
                    const int* __restrict__ tile_e, const int* __restrict__ tile_rt,
                    const int* __restrict__ ntiles, short* __restrict__ aslab) {
  int tile = blockIdx.x, kt = blockIdx.y;
  if (tile >= *ntiles) return;
  int e = tile_e[tile], rt = tile_rt[tile];
  int ne = cnt[e * CNTS];
  int tid = threadIdx.x;
  short* d = aslab + ((size_t)tile * 24 + kt) * 4096;
#pragma unroll
  for (int i = 0; i < 2; i++) {
    int seg = tid + i * 256;
    int row = seg >> 2, p = seg & 3;
    int q = p ^ swz(row);
    int r = rt * 128 + row; if (r >= ne) r = ne - 1;
    int t = tok[e * T_TOK + r];
    const float* src = x + (size_t)t * D_EMB + kt * 32 + q * 8;
    union { short sv[8]; uint4 u; } o;
#pragma unroll
    for (int j = 0; j < 8; j++) o.sv[j] = f2bf(src[j]);
    *(uint4*)&d[(size_t)seg * 8] = o.u;
  }
}

// ---------------- unified depth-3 reg-staged pipeline GEMM (r17, session best) ----------------
// Step t: {global loads tile t+3 -> reg slot R[t%3] ; ds_write R[(t+1)%3] -> L[(t+1)%2]
// (aged ~2 steps; compiler emits COUNTED vmcnt on exactly those regs) ;
// ds_read frags + 16 MFMA from L[t%2] ; lgkmcnt(0) ; sched_barrier ; s_barrier}.
// No __syncthreads in the loop => no vmcnt(0) drain.
// EPI=0 (FC): A from slab (stride 4096/kt), epilogue gelu -> h rows.
// EPI=1 (PROJ): A from h rows (stride 32/kt), epilogue weighted atomicAdd -> out.
template<int KDIM, int NDIM, int SPLITK, int GRT, int GCT, int EPI>
__global__ __launch_bounds__(256, 2)
void pipe_gemm(const short* __restrict__ Aop, const short* __restrict__ Bslab,
               const int* __restrict__ tok, const float* __restrict__ wgt,
               const int* __restrict__ cnt, const int* __restrict__ offs,
               const int* __restrict__ tile_e, const int* __restrict__ tile_rt,
               const int* __restrict__ ntiles,
               short* __restrict__ hout, float* __restrict__ fout) {
  const int COLT = NDIM / 128;
  const int KS = KDIM / SPLITK;
  const int NKT = KS / 32;                 // FC 24, PROJ 48
  const int NKTALL = KDIM / 32;
  const int ASTRIDE = (EPI == 0) ? 4096 : 32;
  const int BPS = GRT * GCT;
  const int NCG = COLT / GCT;
  const int PER_SK = MAXT * COLT;
  static_assert(NKT % 6 == 0 && NKT >= 12, "depth-3 pipeline needs NKT%6==0");

  int nwg = gridDim.x, cpx = nwg >> 3;
  int logical = (blockIdx.x & 7) * cpx + (blockIdx.x >> 3);   // bijective XCD swizzle
  int sk = logical / PER_SK;
  int rem = logical % PER_SK;
  int super = rem / BPS, inner = rem % BPS;
  int band = super / NCG, cg = super % NCG;
  int tile = band * GRT + (inner % GRT);
  int ct = cg * GCT + (inner / GRT);
  if (tile >= *ntiles) return;
  int e = tile_e[tile], rt = tile_rt[tile];
  int ne = cnt[e * CNTS];
  int base = offs[e];

  __shared__ __align__(16) short As[2][4096];
  __shared__ __align__(16) short Bs[2][4096];

  int tid = threadIdx.x, lane = tid & 63, wid = tid >> 6;
  int wr = (wid >> 1) * 64, wc = (wid & 1) * 64;
  int cb = lane >> 4;

  const short* ap0;
  const short* ap1;
  if (EPI == 0) {
    ap0 = Aop + (size_t)tile * NKTALL * 4096 + tid * 8;
    ap1 = ap0 + 2048;
  } else {
    {
      int seg = tid;
      int row = seg >> 2, p = seg & 3;
      int q = p ^ swz(row);
      int r = rt * 128 + row; if (r >= ne) r = ne - 1;
      ap0 = Aop + (size_t)(base + r) * KDIM + sk * KS + q * 8;
    }
    {
      int seg = tid + 256;
      int row = seg >> 2, p = seg & 3;
      int q = p ^ swz(row);
      int r = rt * 128 + row; if (r >= ne) r = ne - 1;
      ap1 = Aop + (size_t)(base + r) * KDIM + sk * KS + q * 8;
    }
  }
  const short* bp0 = Bslab + (((size_t)e * COLT + ct) * NKTALL + sk * NKT) * 4096 + tid * 8;
  const short* bp1 = bp0 + 2048;
  int lo0 = tid * 8, lo1 = (tid + 256) * 8;

  int offa[4], offb[4];
#pragma unroll
  for (int m = 0; m < 4; m++) {
    int row = wr + m * 16 + (lane & 15);
    offa[m] = row * 32 + ((cb ^ swz(row)) * 8);
  }
#pragma unroll
  for (int n = 0; n < 4; n++) {
    int row = wc + n * 16 + (lane & 15);
    offb[n] = row * 32 + ((cb ^ swz(row)) * 8);
  }

  f32x4 acc[4][4];
#pragma unroll
  for (int m = 0; m < 4; m++)
#pragma unroll
    for (int n = 0; n < 4; n++) acc[m][n] = (f32x4){0.f, 0.f, 0.f, 0.f};

  // 3 named register tile-slots (no runtime indexing -> no scratch)
  f32x4 rA0a, rA0b, rB0a, rB0b;
  f32x4 rA1a, rA1b, rB1a, rB1b;
  f32x4 rA2a, rA2b, rB2a, rB2b;

#define LOADS(LA0, LA1, LB0, LB1, KT) do {                                    \
    LA0 = *(const f32x4*)(ap0 + (size_t)(KT) * ASTRIDE);                      \
    LA1 = *(const f32x4*)(ap1 + (size_t)(KT) * ASTRIDE);                      \
    LB0 = *(const f32x4*)(bp0 + (size_t)(KT) * 4096);                        \
    LB1 = *(const f32x4*)(bp1 + (size_t)(KT) * 4096);                        \
  } while (0)
#define WRITES(WA0, WA1, WB0, WB1, LW) do {                                   \
    *(f32x4*)&As[LW][lo0] = WA0; *(f32x4*)&As[LW][lo1] = WA1;                 \
    *(f32x4*)&Bs[LW][lo0] = WB0; *(f32x4*)&Bs[LW][lo1] = WB1;                 \
  } while (0)
#define COMPUTE(LR) do {                                                      \
    bf16x8 af_[4], bv_[4];                                                    \
    _Pragma("unroll") for (int m_ = 0; m_ < 4; ++m_)                          \
      af_[m_] = *(const bf16x8*)&As[LR][offa[m_]];                            \
    _Pragma("unroll") for (int n_ = 0; n_ < 4; ++n_)                          \
      bv_[n_] = *(const bf16x8*)&Bs[LR][offb[n_]];                            \
    _Pragma("unroll") for (int m_ = 0; m_ < 4; ++m_)                          \
      _Pragma("unroll") for (int n_ = 0; n_ < 4; ++n_)                        \
        acc[m_][n_] = __builtin_amdgcn_mfma_f32_16x16x32_bf16(                \
            af_[m_], bv_[n_], acc[m_][n_], 0, 0, 0);                          \
  } while (0)
#define ENDSTEP() do {                                                        \
    asm volatile("s_waitcnt lgkmcnt(0)" ::: "memory");                        \
    __builtin_amdgcn_sched_barrier(0);                                        \
    __builtin_amdgcn_s_barrier();                                             \
  } while (0)
#define STEP(LR, LW, WA0, WA1, WB0, WB1, LA0, LA1, LB0, LB1, KT, DOLD, DOWR) do { \
    if (DOLD) LOADS(LA0, LA1, LB0, LB1, (KT));                                \
    if (DOWR) WRITES(WA0, WA1, WB0, WB1, (LW));                               \
    COMPUTE(LR);                                                              \
    ENDSTEP();                                                                \
  } while (0)

  // prologue: T0->R0, T1->R1, T2->R2; write T0 -> L0
  LOADS(rA0a, rA0b, rB0a, rB0b, 0);
  LOADS(rA1a, rA1b, rB1a, rB1b, 1);
  LOADS(rA2a, rA2b, rB2a, rB2b, 2);
  WRITES(rA0a, rA0b, rB0a, rB0b, 0);
  ENDSTEP();

#pragma unroll 1
  for (int g = 0; g < NKT / 6 - 1; ++g) {
    int kb = 6 * g;
    STEP(0, 1, rA1a, rA1b, rB1a, rB1b, rA0a, rA0b, rB0a, rB0b, kb + 3, 1, 1);
    STEP(1, 0, rA2a, rA2b, rB2a, rB2b, rA1a, rA1b, rB1a, rB1b, kb + 4, 1, 1);
    STEP(0, 1, rA0a, rA0b, rB0a, rB0b, rA2a, rA2b, rB2a, rB2b, kb + 5, 1, 1);
    STEP(1, 0, rA1a, rA1b, rB1a, rB1b, rA0a, rA0b, rB0a, rB0b, kb + 6, 1, 1);
    STEP(0, 1, rA2a, rA2b, rB2a, rB2b, rA1a, rA1b, rB1a, rB1b, kb + 7, 1, 1);
    STEP(1, 0, rA0a, rA0b, rB0a, rB0b, rA2a, rA2b, rB2a, rB2b, kb + 8, 1, 1);
  }
  // tail: t = NKT-6 .. NKT-1
  STEP(0, 1, rA1a, rA1b, rB1a, rB1b, rA0a, rA0b, rB0a, rB0b, NKT - 3, 1, 1);
  STEP(1, 0, rA2a, rA2b, rB2a, rB2b, rA1a, rA1b, rB1a, rB1b, NKT - 2, 1, 1);
  STEP(0, 1, rA0a, rA0b, rB0a, rB0b, rA2a, rA2b, rB2a, rB2b, NKT - 1, 1, 1);
  STEP(1, 0, rA1a, rA1b, rB1a, rB1b, rA0a, rA0b, rB0a, rB0b, 0, 0, 1);
  STEP(0, 1, rA2a, rA2b, rB2a, rB2b, rA1a, rA1b, rB1a, rB1b, 0, 0, 1);
  STEP(1, 0, rA0a, rA0b, rB0a, rB0b, rA2a, rA2b, rB2a, rB2b, 0, 0, 0);

#undef STEP
#undef ENDSTEP
#undef COMPUTE
#undef WRITES
#undef LOADS

  int colbase = ct * 128 + wc;
#pragma unroll
  for (int m = 0; m < 4; m++) {
#pragma unroll
    for (int j = 0; j < 4; j++) {
      int rloc = rt * 128 + wr + m * 16 + ((lane >> 4) << 2) + j;
      if (rloc < ne) {
        if (EPI == 0) {
          size_t hrow = (size_t)(base + rloc) * NDIM;
#pragma unroll
          for (int n = 0; n < 4; n++)
            hout[hrow + colbase + n * 16 + (lane & 15)] = f2bf(gelu_f(acc[m][n][j]));
        } else {
          int t = tok[e * T_TOK + rloc];
          float w = wgt[e * T_TOK + rloc];
          float* orow = fout + (size_t)t * NDIM + colbase + (lane & 15);
#pragma unroll
          for (int n = 0; n < 4; n++)
            atomicAdd(orow + n * 16, w * acc[m][n][j]);
        }
      }
    }
  }
}

extern "C" void kernel_launch(void* const* d_in, const int* in_sizes, int n_in,
                              void* d_out, int out_size, void* d_ws, size_t ws_size,
                              hipStream_t stream) {
  const float* x   = (const float*)d_in[0];
  const float* gw  = (const float*)d_in[1];
  const float* wfc = (const float*)d_in[2];
  const float* wpj = (const float*)d_in[3];
  float* out = (float*)d_out;

  char* ws = (char*)d_ws;
  const size_t SZ_ASLAB = (size_t)MAXT * 24 * 4096 * 2;        // 14,155,776
  const size_t SZ_BFC   = (size_t)N_EXP * 24 * 24 * 4096 * 2;  // 37,748,736
  const size_t SZ_BPJ   = (size_t)N_EXP * 6 * 96 * 4096 * 2;   // 37,748,736
  const size_t SZ_H     = (size_t)2 * T_TOK * DFF * 2;         // 50,331,648
  short* aslab = (short*)(ws);
  short* bfc   = (short*)(ws + SZ_ASLAB);
  short* bpj   = (short*)(ws + SZ_ASLAB + SZ_BFC);
  short* h     = (short*)(ws + SZ_ASLAB + SZ_BFC + SZ_BPJ);
  char* p2     = ws + SZ_ASLAB + SZ_BFC + SZ_BPJ + SZ_H;
  int*   tok  = (int*)(p2);
  float* wgt  = (float*)(p2 + (size_t)N_EXP * T_TOK * 4);
  char* p3    = p2 + (size_t)N_EXP * T_TOK * 8;
  int*   cnt     = (int*)(p3);
  int*   offs    = (int*)(p3 + 1024);
  int*   tile_e  = (int*)(p3 + 1024 + 64);
  int*   tile_rt = (int*)(p3 + 1024 + 64 + 512);
  int*   ntiles  = (int*)(p3 + 1024 + 64 + 1024);

  int n4 = out_size / 4;
  zero_init_kernel<<<2048, 256, 0, stream>>>((float4*)out, n4, cnt);
  slab_weights<<<dim3(24, 24, N_EXP), 256, 0, stream>>>(wfc, bfc, D_EMB, DFF, 24, 24);
  slab_weights<<<dim3(6, 96, N_EXP), 256, 0, stream>>>(wpj, bpj, DFF, D_EMB, 6, 96);
  gate_kernel<<<T_TOK / 16, 256, 0, stream>>>(x, gw, cnt, tok, wgt);
  plan_kernel<<<1, 1, 0, stream>>>(cnt, offs, tile_e, tile_rt, ntiles);
  gatherA_kernel<<<dim3(MAXT, 24), 256, 0, stream>>>(x, tok, cnt, offs, tile_e, tile_rt, ntiles, aslab);
  // FC: depth-3 pipe, A=slab. K=768 (NKT=24), N=3072. grid = 72*24 = 1728 (%8==0)
  pipe_gemm<D_EMB, DFF, 1, 8, 8, 0><<<MAXT * (DFF / 128), 256, 0, stream>>>(
      aslab, bfc, tok, wgt, cnt, offs, tile_e, tile_rt, ntiles, h, nullptr);
  // PROJ: depth-3 pipe, A=h rows. K=3072 split 2 (NKT=48), N=768. grid = 864 (%8==0)
  pipe_gemm<DFF, D_EMB, 2, 8, 6, 1><<<2 * MAXT * (D_EMB / 128), 256, 0, stream>>>(
      h, bpj, tok, wgt, cnt, offs, tile_e, tile_rt, ntiles, nullptr, out);
}

// Round 23
// 213.348 us; speedup vs baseline: 1.2001x; 1.0066x over previous
//
#include <hip/hip_runtime.h>
#include <hip/hip_bf16.h>
#include <math.h>

#define T_TOK 4096
#define D_EMB 768
#define DFF   3072
#define N_EXP 8
#define MAXT  72
#define CNTS  16

typedef __attribute__((ext_vector_type(8))) short bf16x8;
typedef __attribute__((ext_vector_type(4))) float f32x4;

__device__ __forceinline__ short f2bf(float f) {
  union { __hip_bfloat16 b; short s; } u;
  u.b = __float2bfloat16(f);
  return u.s;
}

// tanh-form GELU (validated r9/r14/r16/r17)
__device__ __forceinline__ float gelu_f(float v) {
  float u = 0.7978845608f * v * (1.0f + 0.044715f * v * v);
  float a = fabsf(u);
  float em = __expf(-2.0f * a);
  float th = (1.0f - em) / (1.0f + em);
  th = (u < 0.0f) ? -th : th;
  return 0.5f * v * (1.0f + th);
}

__device__ __forceinline__ int swz(int row) { return (row ^ (row >> 2)) & 3; }

// ---------------- zero out + counters ----------------
__global__ void zero_init_kernel(float4* __restrict__ out4, int n4, int* __restrict__ cnt) {
  int i = blockIdx.x * blockDim.x + threadIdx.x;
  if (i < N_EXP * CNTS) cnt[i] = 0;
  float4 z; z.x = z.y = z.z = z.w = 0.f;
  for (int j = i; j < n4; j += gridDim.x * blockDim.x) out4[j] = z;
}

// ---------------- weight -> slab transform (r14, validated) ----------------
__global__ __launch_bounds__(256)
void slab_weights(const float* __restrict__ src, short* __restrict__ dst,
                  int Kt, int Nt, int NCT, int NKTall) {
  __shared__ float t32[32][132];
  int ct = blockIdx.x, kt = blockIdx.y, e = blockIdx.z;
  const float* s = src + ((size_t)e * Kt + kt * 32) * Nt + ct * 128;
  int tid = threadIdx.x;
#pragma unroll
  for (int p4 = 0; p4 < 4; p4++) {
    int idx = tid + p4 * 256;
    int kl = idx >> 5, c4 = idx & 31;
    float4 v = *(const float4*)&s[(size_t)kl * Nt + c4 * 4];
    t32[kl][c4 * 4 + 0] = v.x; t32[kl][c4 * 4 + 1] = v.y;
    t32[kl][c4 * 4 + 2] = v.z; t32[kl][c4 * 4 + 3] = v.w;
  }
  __syncthreads();
  short* d = dst + (((size_t)e * NCT + ct) * NKTall + kt) * 4096;
#pragma unroll
  for (int i = 0; i < 2; i++) {
    int seg = tid + i * 256;
    int row = seg >> 2, p = seg & 3;
    int q = p ^ swz(row);
    union { short sv[8]; uint4 u; } o;
#pragma unroll
    for (int j = 0; j < 8; j++) o.sv[j] = f2bf(t32[q * 8 + j][row]);
    *(uint4*)&d[(size_t)seg * 8] = o.u;
  }
}

// ---------------- gate (validated) ----------------
__global__ __launch_bounds__(256)
void gate_kernel(const float* __restrict__ x, const float* __restrict__ gw,
                 int* __restrict__ cnt, int* __restrict__ tok,
                 float* __restrict__ wgt) {
  __shared__ int lcnt[N_EXP];
  __shared__ int gbase[N_EXP];
  __shared__ int le[32];
  __shared__ float lw[32];
  __shared__ int lpos[32];
  int tid = threadIdx.x, lane = tid & 63, wid = tid >> 6;
  if (tid < N_EXP) lcnt[tid] = 0;
  __syncthreads();

#pragma unroll
  for (int i = 0; i < 4; i++) {
    int t = blockIdx.x * 16 + wid * 4 + i;
    float s[N_EXP];
#pragma unroll
    for (int e = 0; e < N_EXP; e++) s[e] = 0.f;
#pragma unroll
    for (int dd = 0; dd < D_EMB / 64; dd++) {
      int d = dd * 64 + lane;
      float xv = x[(size_t)t * D_EMB + d];
#pragma unroll
      for (int e = 0; e < N_EXP; e++) s[e] += xv * gw[d * N_EXP + e];
    }
#pragma unroll
    for (int e = 0; e < N_EXP; e++) {
#pragma unroll
      for (int off = 32; off > 0; off >>= 1) s[e] += __shfl_xor(s[e], off, 64);
    }
    if (lane == 0) {
      int e0 = 0;
#pragma unroll
      for (int e = 1; e < N_EXP; e++) if (s[e] > s[e0]) e0 = e;
      int e1 = -1;
#pragma unroll
      for (int e = 0; e < N_EXP; e++) {
        if (e == e0) continue;
        if (e1 < 0 || s[e] > s[e1]) e1 = e;
      }
      float p1 = __expf(s[e1] - s[e0]);
      float inv = 1.f / (1.f + p1);
      int idx = (wid * 4 + i) * 2;
      le[idx] = e0; lw[idx] = inv;           lpos[idx] = atomicAdd(&lcnt[e0], 1);
      le[idx + 1] = e1; lw[idx + 1] = p1 * inv; lpos[idx + 1] = atomicAdd(&lcnt[e1], 1);
    }
  }
  __syncthreads();
  if (tid < N_EXP) gbase[tid] = atomicAdd(&cnt[tid * CNTS], lcnt[tid]);
  __syncthreads();
  if (tid < 32) {
    int e = le[tid];
    int t = blockIdx.x * 16 + (tid >> 1);
    int p = gbase[e] + lpos[tid];
    tok[e * T_TOK + p] = t;
    wgt[e * T_TOK + p] = lw[tid];
  }
}

// ---------------- plan ----------------
__global__ void plan_kernel(const int* __restrict__ cnt, int* __restrict__ offs,
                            int* __restrict__ tile_e, int* __restrict__ tile_rt,
                            int* __restrict__ ntiles) {
  if (threadIdx.x != 0 || blockIdx.x != 0) return;
  int o = 0, nt = 0;
  for (int e = 0; e < N_EXP; e++) {
    offs[e] = o;
    int tc = (cnt[e * CNTS] + 127) >> 7;
    for (int i = 0; i < tc; i++) { tile_e[nt] = e; tile_rt[nt] = i; nt++; }
    o += cnt[e * CNTS];
  }
  *ntiles = nt;
}

// ---------------- A-slab gather (r14, validated) ----------------
__global__ __launch_bounds__(256)
void gatherA_kernel(const float* __restrict__ x, const int* __restrict__ tok,
                    const int* __restrict__ cnt, const int* __restrict__ offs,
                    const int* __restrict__ tile_e, const int* __restrict__ tile_rt,
                    const int* __restrict__ ntiles, short* __restrict__ aslab) {
  int tile = blockIdx.x, kt = blockIdx.y;
  if (tile >= *ntiles) return;
  int e = tile_e[tile], rt = tile_rt[tile];
  int ne = cnt[e * CNTS];
  int tid = threadIdx.x;
  short* d = aslab + ((size_t)tile * 24 + kt) * 4096;
#pragma unroll
  for (int i = 0; i < 2; i++) {
    int seg = tid + i * 256;
    int row = seg >> 2, p = seg & 3;
    int q = p ^ swz(row);
    int r = rt * 128 + row; if (r >= ne) r = ne - 1;
    int t = tok[e * T_TOK + r];
    const float* src = x + (size_t)t * D_EMB + kt * 32 + q * 8;
    union { short sv[8]; uint4 u; } o;
#pragma unroll
    for (int j = 0; j < 8; j++) o.sv[j] = f2bf(src[j]);
    *(uint4*)&d[(size_t)seg * 8] = o.u;
  }
}

// ---------------- depth-3 pipe with 3 LDS buffers + DEFERRED write-drain ----------------
// Step t: {COMPUTE L[t%3] (8 ds_read + 16 MFMA); WRITE tile t+2 (slot[(t+2)%3]) ->
// L[(t+2)%3]; LOAD tile t+3 -> slot[t%3]; s_waitcnt lgkmcnt(4); s_barrier}.
// The counted lgkmcnt(4) leaves THIS step's 4 ds_writes in flight across the
// barrier (their buffer is read only at t+2; in-order DS retirement means t's
// writes are drained by t+1's lgkmcnt(4) - one barrier before their readers).
// 48 KB LDS -> 3 blocks/CU (vs 2) for extra TLP.
template<int KDIM, int NDIM, int SPLITK, int GRT, int GCT, int EPI>
__global__ __launch_bounds__(256, 3)
void pipe_gemm(const short* __restrict__ Aop, const short* __restrict__ Bslab,
               const int* __restrict__ tok, const float* __restrict__ wgt,
               const int* __restrict__ cnt, const int* __restrict__ offs,
               const int* __restrict__ tile_e, const int* __restrict__ tile_rt,
               const int* __restrict__ ntiles,
               short* __restrict__ hout, float* __restrict__ fout) {
  const int COLT = NDIM / 128;
  const int KS = KDIM / SPLITK;
  const int NKT = KS / 32;                 // FC 24, PROJ 48
  const int NKTALL = KDIM / 32;
  const int ASTRIDE = (EPI == 0) ? 4096 : 32;
  const int BPS = GRT * GCT;
  const int NCG = COLT / GCT;
  const int PER_SK = MAXT * COLT;
  static_assert(NKT % 3 == 0 && NKT >= 9, "3-buffer pipeline needs NKT%3==0");

  int nwg = gridDim.x, cpx = nwg >> 3;
  int logical = (blockIdx.x & 7) * cpx + (blockIdx.x >> 3);   // bijective XCD swizzle
  int sk = logical / PER_SK;
  int rem = logical % PER_SK;
  int super = rem / BPS, inner = rem % BPS;
  int band = super / NCG, cg = super % NCG;
  int tile = band * GRT + (inner % GRT);
  int ct = cg * GCT + (inner / GRT);
  if (tile >= *ntiles) return;
  int e = tile_e[tile], rt = tile_rt[tile];
  int ne = cnt[e * CNTS];
  int base = offs[e];

  __shared__ __align__(16) short As[3][4096];
  __shared__ __align__(16) short Bs[3][4096];

  int tid = threadIdx.x, lane = tid & 63, wid = tid >> 6;
  int wr = (wid >> 1) * 64, wc = (wid & 1) * 64;
  int cb = lane >> 4;

  const short* ap0;
  const short* ap1;
  if (EPI == 0) {
    ap0 = Aop + (size_t)tile * NKTALL * 4096 + tid * 8;
    ap1 = ap0 + 2048;
  } else {
    {
      int seg = tid;
      int row = seg >> 2, p = seg & 3;
      int q = p ^ swz(row);
      int r = rt * 128 + row; if (r >= ne) r = ne - 1;
      ap0 = Aop + (size_t)(base + r) * KDIM + sk * KS + q * 8;
    }
    {
      int seg = tid + 256;
      int row = seg >> 2, p = seg & 3;
      int q = p ^ swz(row);
      int r = rt * 128 + row; if (r >= ne) r = ne - 1;
      ap1 = Aop + (size_t)(base + r) * KDIM + sk * KS + q * 8;
    }
  }
  const short* bp0 = Bslab + (((size_t)e * COLT + ct) * NKTALL + sk * NKT) * 4096 + tid * 8;
  const short* bp1 = bp0 + 2048;
  int lo0 = tid * 8, lo1 = (tid + 256) * 8;

  int offa[4], offb[4];
#pragma unroll
  for (int m = 0; m < 4; m++) {
    int row = wr + m * 16 + (lane & 15);
    offa[m] = row * 32 + ((cb ^ swz(row)) * 8);
  }
#pragma unroll
  for (int n = 0; n < 4; n++) {
    int row = wc + n * 16 + (lane & 15);
    offb[n] = row * 32 + ((cb ^ swz(row)) * 8);
  }

  f32x4 acc[4][4];
#pragma unroll
  for (int m = 0; m < 4; m++)
#pragma unroll
    for (int n = 0; n < 4; n++) acc[m][n] = (f32x4){0.f, 0.f, 0.f, 0.f};

  // 3 named register tile-slots (tile k lives in slot k%3)
  f32x4 rA0a, rA0b, rB0a, rB0b;
  f32x4 rA1a, rA1b, rB1a, rB1b;
  f32x4 rA2a, rA2b, rB2a, rB2b;

#define LOADS(LA0, LA1, LB0, LB1, KT) do {                                    \
    LA0 = *(const f32x4*)(ap0 + (size_t)(KT) * ASTRIDE);                      \
    LA1 = *(const f32x4*)(ap1 + (size_t)(KT) * ASTRIDE);                      \
    LB0 = *(const f32x4*)(bp0 + (size_t)(KT) * 4096);                        \
    LB1 = *(const f32x4*)(bp1 + (size_t)(KT) * 4096);                        \
  } while (0)
#define WRITES(WA0, WA1, WB0, WB1, LW) do {                                   \
    *(f32x4*)&As[LW][lo0] = WA0; *(f32x4*)&As[LW][lo1] = WA1;                 \
    *(f32x4*)&Bs[LW][lo0] = WB0; *(f32x4*)&Bs[LW][lo1] = WB1;                 \
  } while (0)
#define COMPUTE(LR) do {                                                      \
    bf16x8 af_[4], bv_[4];                                                    \
    _Pragma("unroll") for (int m_ = 0; m_ < 4; ++m_)                          \
      af_[m_] = *(const bf16x8*)&As[LR][offa[m_]];                            \
    _Pragma("unroll") for (int n_ = 0; n_ < 4; ++n_)                          \
      bv_[n_] = *(const bf16x8*)&Bs[LR][offb[n_]];                            \
    _Pragma("unroll") for (int m_ = 0; m_ < 4; ++m_)                          \
      _Pragma("unroll") for (int n_ = 0; n_ < 4; ++n_)                        \
        acc[m_][n_] = __builtin_amdgcn_mfma_f32_16x16x32_bf16(                \
            af_[m_], bv_[n_], acc[m_][n_], 0, 0, 0);                          \
  } while (0)
#define END4() do {                                                           \
    asm volatile("s_waitcnt lgkmcnt(4)" ::: "memory");                        \
    __builtin_amdgcn_sched_barrier(0);                                        \
    __builtin_amdgcn_s_barrier();                                             \
  } while (0)
#define END0() do {                                                           \
    asm volatile("s_waitcnt lgkmcnt(0)" ::: "memory");                        \
    __builtin_amdgcn_sched_barrier(0);                                        \
    __builtin_amdgcn_s_barrier();                                             \
  } while (0)

  // prologue: tiles 0,1,2 -> slots 0,1,2; write tiles 0,1 -> L0,L1; full drain.
  LOADS(rA0a, rA0b, rB0a, rB0b, 0);
  LOADS(rA1a, rA1b, rB1a, rB1b, 1);
  LOADS(rA2a, rA2b, rB2a, rB2b, 2);
  WRITES(rA0a, rA0b, rB0a, rB0b, 0);
  WRITES(rA1a, rA1b, rB1a, rB1b, 1);
  END0();

  // main loop: t = 0 .. NKT-7 in groups of 3.
  // step t: COMPUTE L[t%3]; WRITE slot[(t+2)%3] -> L[(t+2)%3]; LOAD t+3 -> slot[t%3].
#pragma unroll 1
  for (int g = 0; g < (NKT - 6) / 3; ++g) {
    int kb = 3 * g;
    COMPUTE(0); WRITES(rA2a, rA2b, rB2a, rB2b, 2); LOADS(rA0a, rA0b, rB0a, rB0b, kb + 3); END4();
    COMPUTE(1); WRITES(rA0a, rA0b, rB0a, rB0b, 0); LOADS(rA1a, rA1b, rB1a, rB1b, kb + 4); END4();
    COMPUTE(2); WRITES(rA1a, rA1b, rB1a, rB1b, 1); LOADS(rA2a, rA2b, rB2a, rB2b, kb + 5); END4();
  }
  // tail: t = NKT-6 .. NKT-1
  COMPUTE(0); WRITES(rA2a, rA2b, rB2a, rB2b, 2); LOADS(rA0a, rA0b, rB0a, rB0b, NKT - 3); END4();
  COMPUTE(1); WRITES(rA0a, rA0b, rB0a, rB0b, 0); LOADS(rA1a, rA1b, rB1a, rB1b, NKT - 2); END4();
  COMPUTE(2); WRITES(rA1a, rA1b, rB1a, rB1b, 1); LOADS(rA2a, rA2b, rB2a, rB2b, NKT - 1); END4();
  COMPUTE(0); WRITES(rA2a, rA2b, rB2a, rB2b, 2); END4();   // writes tile NKT-1
  COMPUTE(1); END0();                                      // drain all writes
  COMPUTE(2);                                              // last tile

#undef END0
#undef END4
#undef COMPUTE
#undef WRITES
#undef LOADS

  int colbase = ct * 128 + wc;
#pragma unroll
  for (int m = 0; m < 4; m++) {
#pragma unroll
    for (int j = 0; j < 4; j++) {
      int rloc = rt * 128 + wr + m * 16 + ((lane >> 4) << 2) + j;
      if (rloc < ne) {
        if (EPI == 0) {
          size_t hrow = (size_t)(base + rloc) * NDIM;
#pragma unroll
          for (int n = 0; n < 4; n++)
            hout[hrow + colbase + n * 16 + (lane & 15)] = f2bf(gelu_f(acc[m][n][j]));
        } else {
          int t = tok[e * T_TOK + rloc];
          float w = wgt[e * T_TOK + rloc];
          float* orow = fout + (size_t)t * NDIM + colbase + (lane & 15);
#pragma unroll
          for (int n = 0; n < 4; n++)
            atomicAdd(orow + n * 16, w * acc[m][n][j]);
        }
      }
    }
  }
}

extern "C" void kernel_launch(void* const* d_in, const int* in_sizes, int n_in,
                              void* d_out, int out_size, void* d_ws, size_t ws_size,
                              hipStream_t stream) {
  const float* x   = (const float*)d_in[0];
  const float* gw  = (const float*)d_in[1];
  const float* wfc = (const float*)d_in[2];
  const float* wpj = (const float*)d_in[3];
  float* out = (float*)d_out;

  char* ws = (char*)d_ws;
  const size_t SZ_ASLAB = (size_t)MAXT * 24 * 4096 * 2;        // 14,155,776
  const size_t SZ_BFC   = (size_t)N_EXP * 24 * 24 * 4096 * 2;  // 37,748,736
  const size_t SZ_BPJ   = (size_t)N_EXP * 6 * 96 * 4096 * 2;   // 37,748,736
  const size_t SZ_H     = (size_t)2 * T_TOK * DFF * 2;         // 50,331,648
  short* aslab = (short*)(ws);
  short* bfc   = (short*)(ws + SZ_ASLAB);
  short* bpj   = (short*)(ws + SZ_ASLAB + SZ_BFC);
  short* h     = (short*)(ws + SZ_ASLAB + SZ_BFC + SZ_BPJ);
  char* p2     = ws + SZ_ASLAB + SZ_BFC + SZ_BPJ + SZ_H;
  int*   tok  = (int*)(p2);
  float* wgt  = (float*)(p2 + (size_t)N_EXP * T_TOK * 4);
  char* p3    = p2 + (size_t)N_EXP * T_TOK * 8;
  int*   cnt     = (int*)(p3);
  int*   offs    = (int*)(p3 + 1024);
  int*   tile_e  = (int*)(p3 + 1024 + 64);
  int*   tile_rt = (int*)(p3 + 1024 + 64 + 512);
  int*   ntiles  = (int*)(p3 + 1024 + 64 + 1024);

  int n4 = out_size / 4;
  zero_init_kernel<<<2048, 256, 0, stream>>>((float4*)out, n4, cnt);
  slab_weights<<<dim3(24, 24, N_EXP), 256, 0, stream>>>(wfc, bfc, D_EMB, DFF, 24, 24);
  slab_weights<<<dim3(6, 96, N_EXP), 256, 0, stream>>>(wpj, bpj, DFF, D_EMB, 6, 96);
  gate_kernel<<<T_TOK / 16, 256, 0, stream>>>(x, gw, cnt, tok, wgt);
  plan_kernel<<<1, 1, 0, stream>>>(cnt, offs, tile_e, tile_rt, ntiles);
  gatherA_kernel<<<dim3(MAXT, 24), 256, 0, stream>>>(x, tok, cnt, offs, tile_e, tile_rt, ntiles, aslab);
  // FC: 3-buffer deferred-drain pipe, A=slab. K=768 (NKT=24). grid = 1728 (%8==0)
  pipe_gemm<D_EMB, DFF, 1, 8, 8, 0><<<MAXT * (DFF / 128), 256, 0, stream>>>(
      aslab, bfc, tok, wgt, cnt, offs, tile_e, tile_rt, ntiles, h, nullptr);
  // PROJ: same, A=h rows. K=3072 split 2 (NKT=48). grid = 864 (%8==0)
  pipe_gemm<DFF, D_EMB, 2, 8, 6, 1><<<2 * MAXT * (D_EMB / 128), 256, 0, stream>>>(
      h, bpj, tok, wgt, cnt, offs, tile_e, tile_rt, ntiles, nullptr, out);
}

// Round 24
// 207.458 us; speedup vs baseline: 1.2341x; 1.0284x over previous
//
#include <hip/hip_runtime.h>
#include <hip/hip_bf16.h>
#include <math.h>

#define T_TOK 4096
#define D_EMB 768
#define DFF   3072
#define N_EXP 8
#define MAXT  72
#define CNTS  16

typedef __attribute__((ext_vector_type(8))) short bf16x8;
typedef __attribute__((ext_vector_type(4))) float f32x4;

__device__ __forceinline__ short f2bf(float f) {
  union { __hip_bfloat16 b; short s; } u;
  u.b = __float2bfloat16(f);
  return u.s;
}

// tanh-form GELU (validated r9/r14/r16/r17)
__device__ __forceinline__ float gelu_f(float v) {
  float u = 0.7978845608f * v * (1.0f + 0.044715f * v * v);
  float a = fabsf(u);
  float em = __expf(-2.0f * a);
  float th = (1.0f - em) / (1.0f + em);
  th = (u < 0.0f) ? -th : th;
  return 0.5f * v * (1.0f + th);
}

__device__ __forceinline__ int swz(int row) { return (row ^ (row >> 2)) & 3; }

// ---------------- fused prep: weight->slab (both), out-zero, cnt-zero ----------------
// grid = 2*4608 blocks. bx<4608: wfc slab (NCT=24,NKT=24); else wpj slab (NCT=6,NKT=96).
// Every block also zeroes a stride-slice of out; block 0 zeroes cnt.
__global__ __launch_bounds__(256)
void prep_kernel(const float* __restrict__ wfc, short* __restrict__ bfc,
                 const float* __restrict__ wpj, short* __restrict__ bpj,
                 float4* __restrict__ out4, int n4, int* __restrict__ cnt) {
  __shared__ float t32[32][132];
  int bx = blockIdx.x;
  int tid = threadIdx.x;

  // zero slice of out (12.6 MB over 9216 blocks)
  {
    float4 z; z.x = z.y = z.z = z.w = 0.f;
    int stride = gridDim.x * 256;
    for (int j = bx * 256 + tid; j < n4; j += stride) out4[j] = z;
    if (bx == 0 && tid < N_EXP * CNTS) cnt[tid] = 0;
  }

  const float* src;
  short* dst;
  int ct, kt, e, Kt, Nt, NCT, NKTall;
  if (bx < 4608) {
    ct = bx % 24; kt = (bx / 24) % 24; e = bx / 576;
    src = wfc; dst = bfc; Kt = D_EMB; Nt = DFF; NCT = 24; NKTall = 24;
  } else {
    int b = bx - 4608;
    ct = b % 6; kt = (b / 6) % 96; e = b / 576;
    src = wpj; dst = bpj; Kt = DFF; Nt = D_EMB; NCT = 6; NKTall = 96;
  }
  const float* s = src + ((size_t)e * Kt + kt * 32) * Nt + ct * 128;
#pragma unroll
  for (int p4 = 0; p4 < 4; p4++) {
    int idx = tid + p4 * 256;
    int kl = idx >> 5, c4 = idx & 31;
    float4 v = *(const float4*)&s[(size_t)kl * Nt + c4 * 4];
    t32[kl][c4 * 4 + 0] = v.x; t32[kl][c4 * 4 + 1] = v.y;
    t32[kl][c4 * 4 + 2] = v.z; t32[kl][c4 * 4 + 3] = v.w;
  }
  __syncthreads();
  short* d = dst + (((size_t)e * NCT + ct) * NKTall + kt) * 4096;
#pragma unroll
  for (int i = 0; i < 2; i++) {
    int seg = tid + i * 256;
    int row = seg >> 2, p = seg & 3;
    int q = p ^ swz(row);
    union { short sv[8]; uint4 u; } o;
#pragma unroll
    for (int j = 0; j < 8; j++) o.sv[j] = f2bf(t32[q * 8 + j][row]);
    *(uint4*)&d[(size_t)seg * 8] = o.u;
  }
}

// ---------------- gate (validated) ----------------
__global__ __launch_bounds__(256)
void gate_kernel(const float* __restrict__ x, const float* __restrict__ gw,
                 int* __restrict__ cnt, int* __restrict__ tok,
                 float* __restrict__ wgt) {
  __shared__ int lcnt[N_EXP];
  __shared__ int gbase[N_EXP];
  __shared__ int le[32];
  __shared__ float lw[32];
  __shared__ int lpos[32];
  int tid = threadIdx.x, lane = tid & 63, wid = tid >> 6;
  if (tid < N_EXP) lcnt[tid] = 0;
  __syncthreads();

#pragma unroll
  for (int i = 0; i < 4; i++) {
    int t = blockIdx.x * 16 + wid * 4 + i;
    float s[N_EXP];
#pragma unroll
    for (int e = 0; e < N_EXP; e++) s[e] = 0.f;
#pragma unroll
    for (int dd = 0; dd < D_EMB / 64; dd++) {
      int d = dd * 64 + lane;
      float xv = x[(size_t)t * D_EMB + d];
#pragma unroll
      for (int e = 0; e < N_EXP; e++) s[e] += xv * gw[d * N_EXP + e];
    }
#pragma unroll
    for (int e = 0; e < N_EXP; e++) {
#pragma unroll
      for (int off = 32; off > 0; off >>= 1) s[e] += __shfl_xor(s[e], off, 64);
    }
    if (lane == 0) {
      int e0 = 0;
#pragma unroll
      for (int e = 1; e < N_EXP; e++) if (s[e] > s[e0]) e0 = e;
      int e1 = -1;
#pragma unroll
      for (int e = 0; e < N_EXP; e++) {
        if (e == e0) continue;
        if (e1 < 0 || s[e] > s[e1]) e1 = e;
      }
      float p1 = __expf(s[e1] - s[e0]);
      float inv = 1.f / (1.f + p1);
      int idx = (wid * 4 + i) * 2;
      le[idx] = e0; lw[idx] = inv;           lpos[idx] = atomicAdd(&lcnt[e0], 1);
      le[idx + 1] = e1; lw[idx + 1] = p1 * inv; lpos[idx + 1] = atomicAdd(&lcnt[e1], 1);
    }
  }
  __syncthreads();
  if (tid < N_EXP) gbase[tid] = atomicAdd(&cnt[tid * CNTS], lcnt[tid]);
  __syncthreads();
  if (tid < 32) {
    int e = le[tid];
    int t = blockIdx.x * 16 + (tid >> 1);
    int p = gbase[e] + lpos[tid];
    tok[e * T_TOK + p] = t;
    wgt[e * T_TOK + p] = lw[tid];
  }
}

// ---------------- plan ----------------
__global__ void plan_kernel(const int* __restrict__ cnt, int* __restrict__ offs,
                            int* __restrict__ tile_e, int* __restrict__ tile_rt,
                            int* __restrict__ ntiles) {
  if (threadIdx.x != 0 || blockIdx.x != 0) return;
  int o = 0, nt = 0;
  for (int e = 0; e < N_EXP; e++) {
    offs[e] = o;
    int tc = (cnt[e * CNTS] + 127) >> 7;
    for (int i = 0; i < tc; i++) { tile_e[nt] = e; tile_rt[nt] = i; nt++; }
    o += cnt[e * CNTS];
  }
  *ntiles = nt;
}

// ---------------- A-slab gather (r14, validated) ----------------
__global__ __launch_bounds__(256)
void gatherA_kernel(const float* __restrict__ x, const int* __restrict__ tok,
                    const int* __restrict__ cnt, const int* __restrict__ offs,
                    const int* __restrict__ tile_e, const int* __restrict__ tile_rt,
                    const int* __restrict__ ntiles, short* __restrict__ aslab) {
  int tile = blockIdx.x, kt = blockIdx.y;
  if (tile >= *ntiles) return;
  int e = tile_e[tile], rt = tile_rt[tile];
  int ne = cnt[e * CNTS];
  int tid = threadIdx.x;
  short* d = aslab + ((size_t)tile * 24 + kt) * 4096;
#pragma unroll
  for (int i = 0; i < 2; i++) {
    int seg = tid + i * 256;
    int row = seg >> 2, p = seg & 3;
    int q = p ^ swz(row);
    int r = rt * 128 + row; if (r >= ne) r = ne - 1;
    int t = tok[e * T_TOK + r];
    const float* src = x + (size_t)t * D_EMB + kt * 32 + q * 8;
    union { short sv[8]; uint4 u; } o;
#pragma unroll
    for (int j = 0; j < 8; j++) o.sv[j] = f2bf(src[j]);
    *(uint4*)&d[(size_t)seg * 8] = o.u;
  }
}

// ---------------- depth-3 pipe with 3 LDS buffers + DEFERRED write-drain (r23) ----------------
template<int KDIM, int NDIM, int SPLITK, int GRT, int GCT, int EPI>
__global__ __launch_bounds__(256, 3)
void pipe_gemm(const short* __restrict__ Aop, const short* __restrict__ Bslab,
               const int* __restrict__ tok, const float* __restrict__ wgt,
               const int* __restrict__ cnt, const int* __restrict__ offs,
               const int* __restrict__ tile_e, const int* __restrict__ tile_rt,
               const int* __restrict__ ntiles,
               short* __restrict__ hout, float* __restrict__ fout) {
  const int COLT = NDIM / 128;
  const int KS = KDIM / SPLITK;
  const int NKT = KS / 32;                 // FC 24, PROJ 48
  const int NKTALL = KDIM / 32;
  const int ASTRIDE = (EPI == 0) ? 4096 : 32;
  const int BPS = GRT * GCT;
  const int NCG = COLT / GCT;
  const int PER_SK = MAXT * COLT;
  static_assert(NKT % 3 == 0 && NKT >= 9, "3-buffer pipeline needs NKT%3==0");

  int nwg = gridDim.x, cpx = nwg >> 3;
  int logical = (blockIdx.x & 7) * cpx + (blockIdx.x >> 3);   // bijective XCD swizzle
  int sk = logical / PER_SK;
  int rem = logical % PER_SK;
  int super = rem / BPS, inner = rem % BPS;
  int band = super / NCG, cg = super % NCG;
  int tile = band * GRT + (inner % GRT);
  int ct = cg * GCT + (inner / GRT);
  if (tile >= *ntiles) return;
  int e = tile_e[tile], rt = tile_rt[tile];
  int ne = cnt[e * CNTS];
  int base = offs[e];

  __shared__ __align__(16) short As[3][4096];
  __shared__ __align__(16) short Bs[3][4096];

  int tid = threadIdx.x, lane = tid & 63, wid = tid >> 6;
  int wr = (wid >> 1) * 64, wc = (wid & 1) * 64;
  int cb = lane >> 4;

  const short* ap0;
  const short* ap1;
  if (EPI == 0) {
    ap0 = Aop + (size_t)tile * NKTALL * 4096 + tid * 8;
    ap1 = ap0 + 2048;
  } else {
    {
      int seg = tid;
      int row = seg >> 2, p = seg & 3;
      int q = p ^ swz(row);
      int r = rt * 128 + row; if (r >= ne) r = ne - 1;
      ap0 = Aop + (size_t)(base + r) * KDIM + sk * KS + q * 8;
    }
    {
      int seg = tid + 256;
      int row = seg >> 2, p = seg & 3;
      int q = p ^ swz(row);
      int r = rt * 128 + row; if (r >= ne) r = ne - 1;
      ap1 = Aop + (size_t)(base + r) * KDIM + sk * KS + q * 8;
    }
  }
  const short* bp0 = Bslab + (((size_t)e * COLT + ct) * NKTALL + sk * NKT) * 4096 + tid * 8;
  const short* bp1 = bp0 + 2048;
  int lo0 = tid * 8, lo1 = (tid + 256) * 8;

  int offa[4], offb[4];
#pragma unroll
  for (int m = 0; m < 4; m++) {
    int row = wr + m * 16 + (lane & 15);
    offa[m] = row * 32 + ((cb ^ swz(row)) * 8);
  }
#pragma unroll
  for (int n = 0; n < 4; n++) {
    int row = wc + n * 16 + (lane & 15);
    offb[n] = row * 32 + ((cb ^ swz(row)) * 8);
  }

  f32x4 acc[4][4];
#pragma unroll
  for (int m = 0; m < 4; m++)
#pragma unroll
    for (int n = 0; n < 4; n++) acc[m][n] = (f32x4){0.f, 0.f, 0.f, 0.f};

  // 3 named register tile-slots (tile k lives in slot k%3)
  f32x4 rA0a, rA0b, rB0a, rB0b;
  f32x4 rA1a, rA1b, rB1a, rB1b;
  f32x4 rA2a, rA2b, rB2a, rB2b;

#define LOADS(LA0, LA1, LB0, LB1, KT) do {                                    \
    LA0 = *(const f32x4*)(ap0 + (size_t)(KT) * ASTRIDE);                      \
    LA1 = *(const f32x4*)(ap1 + (size_t)(KT) * ASTRIDE);                      \
    LB0 = *(const f32x4*)(bp0 + (size_t)(KT) * 4096);                        \
    LB1 = *(const f32x4*)(bp1 + (size_t)(KT) * 4096);                        \
  } while (0)
#define WRITES(WA0, WA1, WB0, WB1, LW) do {                                   \
    *(f32x4*)&As[LW][lo0] = WA0; *(f32x4*)&As[LW][lo1] = WA1;                 \
    *(f32x4*)&Bs[LW][lo0] = WB0; *(f32x4*)&Bs[LW][lo1] = WB1;                 \
  } while (0)
#define COMPUTE(LR) do {                                                      \
    bf16x8 af_[4], bv_[4];                                                    \
    _Pragma("unroll") for (int m_ = 0; m_ < 4; ++m_)                          \
      af_[m_] = *(const bf16x8*)&As[LR][offa[m_]];                            \
    _Pragma("unroll") for (int n_ = 0; n_ < 4; ++n_)                          \
      bv_[n_] = *(const bf16x8*)&Bs[LR][offb[n_]];                            \
    _Pragma("unroll") for (int m_ = 0; m_ < 4; ++m_)                          \
      _Pragma("unroll") for (int n_ = 0; n_ < 4; ++n_)                        \
        acc[m_][n_] = __builtin_amdgcn_mfma_f32_16x16x32_bf16(                \
            af_[m_], bv_[n_], acc[m_][n_], 0, 0, 0);                          \
  } while (0)
#define END4() do {                                                           \
    asm volatile("s_waitcnt lgkmcnt(4)" ::: "memory");                        \
    __builtin_amdgcn_sched_barrier(0);                                        \
    __builtin_amdgcn_s_barrier();                                             \
  } while (0)
#define END0() do {                                                           \
    asm volatile("s_waitcnt lgkmcnt(0)" ::: "memory");                        \
    __builtin_amdgcn_sched_barrier(0);                                        \
    __builtin_amdgcn_s_barrier();                                             \
  } while (0)

  // prologue: tiles 0,1,2 -> slots 0,1,2; write tiles 0,1 -> L0,L1; full drain.
  LOADS(rA0a, rA0b, rB0a, rB0b, 0);
  LOADS(rA1a, rA1b, rB1a, rB1b, 1);
  LOADS(rA2a, rA2b, rB2a, rB2b, 2);
  WRITES(rA0a, rA0b, rB0a, rB0b, 0);
  WRITES(rA1a, rA1b, rB1a, rB1b, 1);
  END0();

#pragma unroll 1
  for (int g = 0; g < (NKT - 6) / 3; ++g) {
    int kb = 3 * g;
    COMPUTE(0); WRITES(rA2a, rA2b, rB2a, rB2b, 2); LOADS(rA0a, rA0b, rB0a, rB0b, kb + 3); END4();
    COMPUTE(1); WRITES(rA0a, rA0b, rB0a, rB0b, 0); LOADS(rA1a, rA1b, rB1a, rB1b, kb + 4); END4();
    COMPUTE(2); WRITES(rA1a, rA1b, rB1a, rB1b, 1); LOADS(rA2a, rA2b, rB2a, rB2b, kb + 5); END4();
  }
  // tail: t = NKT-6 .. NKT-1
  COMPUTE(0); WRITES(rA2a, rA2b, rB2a, rB2b, 2); LOADS(rA0a, rA0b, rB0a, rB0b, NKT - 3); END4();
  COMPUTE(1); WRITES(rA0a, rA0b, rB0a, rB0b, 0); LOADS(rA1a, rA1b, rB1a, rB1b, NKT - 2); END4();
  COMPUTE(2); WRITES(rA1a, rA1b, rB1a, rB1b, 1); LOADS(rA2a, rA2b, rB2a, rB2b, NKT - 1); END4();
  COMPUTE(0); WRITES(rA2a, rA2b, rB2a, rB2b, 2); END4();   // writes tile NKT-1
  COMPUTE(1); END0();                                      // drain all writes
  COMPUTE(2);                                              // last tile

#undef END0
#undef END4
#undef COMPUTE
#undef WRITES
#undef LOADS

  int colbase = ct * 128 + wc;
#pragma unroll
  for (int m = 0; m < 4; m++) {
#pragma unroll
    for (int j = 0; j < 4; j++) {
      int rloc = rt * 128 + wr + m * 16 + ((lane >> 4) << 2) + j;
      if (rloc < ne) {
        if (EPI == 0) {
          size_t hrow = (size_t)(base + rloc) * NDIM;
#pragma unroll
          for (int n = 0; n < 4; n++)
            hout[hrow + colbase + n * 16 + (lane & 15)] = f2bf(gelu_f(acc[m][n][j]));
        } else {
          int t = tok[e * T_TOK + rloc];
          float w = wgt[e * T_TOK + rloc];
          float* orow = fout + (size_t)t * NDIM + colbase + (lane & 15);
#pragma unroll
          for (int n = 0; n < 4; n++)
            atomicAdd(orow + n * 16, w * acc[m][n][j]);
        }
      }
    }
  }
}

extern "C" void kernel_launch(void* const* d_in, const int* in_sizes, int n_in,
                              void* d_out, int out_size, void* d_ws, size_t ws_size,
                              hipStream_t stream) {
  const float* x   = (const float*)d_in[0];
  const float* gw  = (const float*)d_in[1];
  const float* wfc = (const float*)d_in[2];
  const float* wpj = (const float*)d_in[3];
  float* out = (float*)d_out;

  char* ws = (char*)d_ws;
  const size_t SZ_ASLAB = (size_t)MAXT * 24 * 4096 * 2;        // 14,155,776
  const size_t SZ_BFC   = (size_t)N_EXP * 24 * 24 * 4096 * 2;  // 37,748,736
  const size_t SZ_BPJ   = (size_t)N_EXP * 6 * 96 * 4096 * 2;   // 37,748,736
  const size_t SZ_H     = (size_t)2 * T_TOK * DFF * 2;         // 50,331,648
  short* aslab = (short*)(ws);
  short* bfc   = (short*)(ws + SZ_ASLAB);
  short* bpj   = (short*)(ws + SZ_ASLAB + SZ_BFC);
  short* h     = (short*)(ws + SZ_ASLAB + SZ_BFC + SZ_BPJ);
  char* p2     = ws + SZ_ASLAB + SZ_BFC + SZ_BPJ + SZ_H;
  int*   tok  = (int*)(p2);
  float* wgt  = (float*)(p2 + (size_t)N_EXP * T_TOK * 4);
  char* p3    = p2 + (size_t)N_EXP * T_TOK * 8;
  int*   cnt     = (int*)(p3);
  int*   offs    = (int*)(p3 + 1024);
  int*   tile_e  = (int*)(p3 + 1024 + 64);
  int*   tile_rt = (int*)(p3 + 1024 + 64 + 512);
  int*   ntiles  = (int*)(p3 + 1024 + 64 + 1024);

  int n4 = out_size / 4;
  // fused: both weight slabs + out-zero + cnt-zero in ONE launch
  prep_kernel<<<2 * 4608, 256, 0, stream>>>(wfc, bfc, wpj, bpj, (float4*)out, n4, cnt);
  gate_kernel<<<T_TOK / 16, 256, 0, stream>>>(x, gw, cnt, tok, wgt);
  plan_kernel<<<1, 1, 0, stream>>>(cnt, offs, tile_e, tile_rt, ntiles);
  gatherA_kernel<<<dim3(MAXT, 24), 256, 0, stream>>>(x, tok, cnt, offs, tile_e, tile_rt, ntiles, aslab);
  // FC: 3-buffer deferred-drain pipe, A=slab. K=768 (NKT=24). grid = 1728 (%8==0)
  pipe_gemm<D_EMB, DFF, 1, 8, 8, 0><<<MAXT * (DFF / 128), 256, 0, stream>>>(
      aslab, bfc, tok, wgt, cnt, offs, tile_e, tile_rt, ntiles, h, nullptr);
  // PROJ: same, A=h rows. K=3072 split 2 (NKT=48). grid = 864 (%8==0)
  pipe_gemm<DFF, D_EMB, 2, 8, 6, 1><<<2 * MAXT * (D_EMB / 128), 256, 0, stream>>>(
      h, bpj, tok, wgt, cnt, offs, tile_e, tile_rt, ntiles, nullptr, out);
}

// Round 25
// 201.946 us; speedup vs baseline: 1.2678x; 1.0273x over previous
//
#include <hip/hip_runtime.h>
#include <hip/hip_bf16.h>
#include <math.h>

#define T_TOK 4096
#define D_EMB 768
#define DFF   3072
#define N_EXP 8
#define MAXT  72
#define CNTS  16

typedef __attribute__((ext_vector_type(8))) short bf16x8;
typedef __attribute__((ext_vector_type(4))) float f32x4;

__device__ __forceinline__ short f2bf(float f) {
  union { __hip_bfloat16 b; short s; } u;
  u.b = __float2bfloat16(f);
  return u.s;
}

// tanh-form GELU (validated r9/r14/r16/r17)
__device__ __forceinline__ float gelu_f(float v) {
  float u = 0.7978845608f * v * (1.0f + 0.044715f * v * v);
  float a = fabsf(u);
  float em = __expf(-2.0f * a);
  float th = (1.0f - em) / (1.0f + em);
  th = (u < 0.0f) ? -th : th;
  return 0.5f * v * (1.0f + th);
}

__device__ __forceinline__ int swz(int row) { return (row ^ (row >> 2)) & 3; }

// inline plan: recompute (e, rt, base, ne) for a row-tile index from cnt[]
// (replaces the serial plan_kernel; ~30 SALU ops on 8 broadcast loads).
__device__ __forceinline__ bool plan_lookup(const int* __restrict__ cnt, int tile,
                                            int& e, int& rt, int& base, int& ne) {
  int acc = 0, o = 0;
  e = -1;
#pragma unroll
  for (int ee = 0; ee < N_EXP; ee++) {
    int c = cnt[ee * CNTS];
    int tc = (c + 127) >> 7;
    if (e < 0 && tile < acc + tc) { e = ee; rt = tile - acc; base = o; ne = c; }
    acc += tc;
    o += c;
  }
  return e >= 0;
}

// ---------------- fused prep: weight->slab (both), out-zero, cnt-zero (r24) ----------------
__global__ __launch_bounds__(256)
void prep_kernel(const float* __restrict__ wfc, short* __restrict__ bfc,
                 const float* __restrict__ wpj, short* __restrict__ bpj,
                 float4* __restrict__ out4, int n4, int* __restrict__ cnt) {
  __shared__ float t32[32][132];
  int bx = blockIdx.x;
  int tid = threadIdx.x;

  {
    float4 z; z.x = z.y = z.z = z.w = 0.f;
    int stride = gridDim.x * 256;
    for (int j = bx * 256 + tid; j < n4; j += stride) out4[j] = z;
    if (bx == 0 && tid < N_EXP * CNTS) cnt[tid] = 0;
  }

  const float* src;
  short* dst;
  int ct, kt, e, Kt, Nt, NCT, NKTall;
  if (bx < 4608) {
    ct = bx % 24; kt = (bx / 24) % 24; e = bx / 576;
    src = wfc; dst = bfc; Kt = D_EMB; Nt = DFF; NCT = 24; NKTall = 24;
  } else {
    int b = bx - 4608;
    ct = b % 6; kt = (b / 6) % 96; e = b / 576;
    src = wpj; dst = bpj; Kt = DFF; Nt = D_EMB; NCT = 6; NKTall = 96;
  }
  const float* s = src + ((size_t)e * Kt + kt * 32) * Nt + ct * 128;
#pragma unroll
  for (int p4 = 0; p4 < 4; p4++) {
    int idx = tid + p4 * 256;
    int kl = idx >> 5, c4 = idx & 31;
    float4 v = *(const float4*)&s[(size_t)kl * Nt + c4 * 4];
    t32[kl][c4 * 4 + 0] = v.x; t32[kl][c4 * 4 + 1] = v.y;
    t32[kl][c4 * 4 + 2] = v.z; t32[kl][c4 * 4 + 3] = v.w;
  }
  __syncthreads();
  short* d = dst + (((size_t)e * NCT + ct) * NKTall + kt) * 4096;
#pragma unroll
  for (int i = 0; i < 2; i++) {
    int seg = tid + i * 256;
    int row = seg >> 2, p = seg & 3;
    int q = p ^ swz(row);
    union { short sv[8]; uint4 u; } o;
#pragma unroll
    for (int j = 0; j < 8; j++) o.sv[j] = f2bf(t32[q * 8 + j][row]);
    *(uint4*)&d[(size_t)seg * 8] = o.u;
  }
}

// ---------------- gate (validated) ----------------
__global__ __launch_bounds__(256)
void gate_kernel(const float* __restrict__ x, const float* __restrict__ gw,
                 int* __restrict__ cnt, int* __restrict__ tok,
                 float* __restrict__ wgt) {
  __shared__ int lcnt[N_EXP];
  __shared__ int gbase[N_EXP];
  __shared__ int le[32];
  __shared__ float lw[32];
  __shared__ int lpos[32];
  int tid = threadIdx.x, lane = tid & 63, wid = tid >> 6;
  if (tid < N_EXP) lcnt[tid] = 0;
  __syncthreads();

#pragma unroll
  for (int i = 0; i < 4; i++) {
    int t = blockIdx.x * 16 + wid * 4 + i;
    float s[N_EXP];
#pragma unroll
    for (int e = 0; e < N_EXP; e++) s[e] = 0.f;
#pragma unroll
    for (int dd = 0; dd < D_EMB / 64; dd++) {
      int d = dd * 64 + lane;
      float xv = x[(size_t)t * D_EMB + d];
#pragma unroll
      for (int e = 0; e < N_EXP; e++) s[e] += xv * gw[d * N_EXP + e];
    }
#pragma unroll
    for (int e = 0; e < N_EXP; e++) {
#pragma unroll
      for (int off = 32; off > 0; off >>= 1) s[e] += __shfl_xor(s[e], off, 64);
    }
    if (lane == 0) {
      int e0 = 0;
#pragma unroll
      for (int e = 1; e < N_EXP; e++) if (s[e] > s[e0]) e0 = e;
      int e1 = -1;
#pragma unroll
      for (int e = 0; e < N_EXP; e++) {
        if (e == e0) continue;
        if (e1 < 0 || s[e] > s[e1]) e1 = e;
      }
      float p1 = __expf(s[e1] - s[e0]);
      float inv = 1.f / (1.f + p1);
      int idx = (wid * 4 + i) * 2;
      le[idx] = e0; lw[idx] = inv;           lpos[idx] = atomicAdd(&lcnt[e0], 1);
      le[idx + 1] = e1; lw[idx + 1] = p1 * inv; lpos[idx + 1] = atomicAdd(&lcnt[e1], 1);
    }
  }
  __syncthreads();
  if (tid < N_EXP) gbase[tid] = atomicAdd(&cnt[tid * CNTS], lcnt[tid]);
  __syncthreads();
  if (tid < 32) {
    int e = le[tid];
    int t = blockIdx.x * 16 + (tid >> 1);
    int p = gbase[e] + lpos[tid];
    tok[e * T_TOK + p] = t;
    wgt[e * T_TOK + p] = lw[tid];
  }
}

// ---------------- A-slab gather (inline plan) ----------------
__global__ __launch_bounds__(256)
void gatherA_kernel(const float* __restrict__ x, const int* __restrict__ tok,
                    const int* __restrict__ cnt, short* __restrict__ aslab) {
  int tile = blockIdx.x, kt = blockIdx.y;
  int e, rt, base, ne;
  if (!plan_lookup(cnt, tile, e, rt, base, ne)) return;
  (void)base;
  int tid = threadIdx.x;
  short* d = aslab + ((size_t)tile * 24 + kt) * 4096;
#pragma unroll
  for (int i = 0; i < 2; i++) {
    int seg = tid + i * 256;
    int row = seg >> 2, p = seg & 3;
    int q = p ^ swz(row);
    int r = rt * 128 + row; if (r >= ne) r = ne - 1;
    int t = tok[e * T_TOK + r];
    const float* src = x + (size_t)t * D_EMB + kt * 32 + q * 8;
    union { short sv[8]; uint4 u; } o;
#pragma unroll
    for (int j = 0; j < 8; j++) o.sv[j] = f2bf(src[j]);
    *(uint4*)&d[(size_t)seg * 8] = o.u;
  }
}

// ---------------- depth-3 pipe, 3 LDS buffers, deferred write-drain (r23/r24) ----------------
template<int KDIM, int NDIM, int SPLITK, int GRT, int GCT, int EPI>
__global__ __launch_bounds__(256, 3)
void pipe_gemm(const short* __restrict__ Aop, const short* __restrict__ Bslab,
               const int* __restrict__ tok, const float* __restrict__ wgt,
               const int* __restrict__ cnt,
               short* __restrict__ hout, float* __restrict__ fout) {
  const int COLT = NDIM / 128;
  const int KS = KDIM / SPLITK;
  const int NKT = KS / 32;                 // FC 24, PROJ 48
  const int NKTALL = KDIM / 32;
  const int ASTRIDE = (EPI == 0) ? 4096 : 32;
  const int BPS = GRT * GCT;
  const int NCG = COLT / GCT;
  const int PER_SK = MAXT * COLT;
  static_assert(NKT % 3 == 0 && NKT >= 9, "3-buffer pipeline needs NKT%3==0");

  int nwg = gridDim.x, cpx = nwg >> 3;
  int logical = (blockIdx.x & 7) * cpx + (blockIdx.x >> 3);   // bijective XCD swizzle
  int sk = logical / PER_SK;
  int rem = logical % PER_SK;
  int super = rem / BPS, inner = rem % BPS;
  int band = super / NCG, cg = super % NCG;
  int tile = band * GRT + (inner % GRT);
  int ct = cg * GCT + (inner / GRT);
  int e, rt, base, ne;
  if (!plan_lookup(cnt, tile, e, rt, base, ne)) return;

  __shared__ __align__(16) short As[3][4096];
  __shared__ __align__(16) short Bs[3][4096];

  int tid = threadIdx.x, lane = tid & 63, wid = tid >> 6;
  int wr = (wid >> 1) * 64, wc = (wid & 1) * 64;
  int cb = lane >> 4;

  const short* ap0;
  const short* ap1;
  if (EPI == 0) {
    ap0 = Aop + (size_t)tile * NKTALL * 4096 + tid * 8;
    ap1 = ap0 + 2048;
  } else {
    {
      int seg = tid;
      int row = seg >> 2, p = seg & 3;
      int q = p ^ swz(row);
      int r = rt * 128 + row; if (r >= ne) r = ne - 1;
      ap0 = Aop + (size_t)(base + r) * KDIM + sk * KS + q * 8;
    }
    {
      int seg = tid + 256;
      int row = seg >> 2, p = seg & 3;
      int q = p ^ swz(row);
      int r = rt * 128 + row; if (r >= ne) r = ne - 1;
      ap1 = Aop + (size_t)(base + r) * KDIM + sk * KS + q * 8;
    }
  }
  const short* bp0 = Bslab + (((size_t)e * COLT + ct) * NKTALL + sk * NKT) * 4096 + tid * 8;
  const short* bp1 = bp0 + 2048;
  int lo0 = tid * 8, lo1 = (tid + 256) * 8;

  int offa[4], offb[4];
#pragma unroll
  for (int m = 0; m < 4; m++) {
    int row = wr + m * 16 + (lane & 15);
    offa[m] = row * 32 + ((cb ^ swz(row)) * 8);
  }
#pragma unroll
  for (int n = 0; n < 4; n++) {
    int row = wc + n * 16 + (lane & 15);
    offb[n] = row * 32 + ((cb ^ swz(row)) * 8);
  }

  f32x4 acc[4][4];
#pragma unroll
  for (int m = 0; m < 4; m++)
#pragma unroll
    for (int n = 0; n < 4; n++) acc[m][n] = (f32x4){0.f, 0.f, 0.f, 0.f};

  // 3 named register tile-slots (tile k lives in slot k%3)
  f32x4 rA0a, rA0b, rB0a, rB0b;
  f32x4 rA1a, rA1b, rB1a, rB1b;
  f32x4 rA2a, rA2b, rB2a, rB2b;

#define LOADS(LA0, LA1, LB0, LB1, KT) do {                                    \
    LA0 = *(const f32x4*)(ap0 + (size_t)(KT) * ASTRIDE);                      \
    LA1 = *(const f32x4*)(ap1 + (size_t)(KT) * ASTRIDE);                      \
    LB0 = *(const f32x4*)(bp0 + (size_t)(KT) * 4096);                        \
    LB1 = *(const f32x4*)(bp1 + (size_t)(KT) * 4096);                        \
  } while (0)
#define WRITES(WA0, WA1, WB0, WB1, LW) do {                                   \
    *(f32x4*)&As[LW][lo0] = WA0; *(f32x4*)&As[LW][lo1] = WA1;                 \
    *(f32x4*)&Bs[LW][lo0] = WB0; *(f32x4*)&Bs[LW][lo1] = WB1;                 \
  } while (0)
#define COMPUTE(LR) do {                                                      \
    bf16x8 af_[4], bv_[4];                                                    \
    _Pragma("unroll") for (int m_ = 0; m_ < 4; ++m_)                          \
      af_[m_] = *(const bf16x8*)&As[LR][offa[m_]];                            \
    _Pragma("unroll") for (int n_ = 0; n_ < 4; ++n_)                          \
      bv_[n_] = *(const bf16x8*)&Bs[LR][offb[n_]];                            \
    _Pragma("unroll") for (int m_ = 0; m_ < 4; ++m_)                          \
      _Pragma("unroll") for (int n_ = 0; n_ < 4; ++n_)                        \
        acc[m_][n_] = __builtin_amdgcn_mfma_f32_16x16x32_bf16(                \
            af_[m_], bv_[n_], acc[m_][n_], 0, 0, 0);                          \
  } while (0)
#define END4() do {                                                           \
    asm volatile("s_waitcnt lgkmcnt(4)" ::: "memory");                        \
    __builtin_amdgcn_sched_barrier(0);                                        \
    __builtin_amdgcn_s_barrier();                                             \
  } while (0)
#define END0() do {                                                           \
    asm volatile("s_waitcnt lgkmcnt(0)" ::: "memory");                        \
    __builtin_amdgcn_sched_barrier(0);                                        \
    __builtin_amdgcn_s_barrier();                                             \
  } while (0)

  // prologue: tiles 0,1,2 -> slots 0,1,2; write tiles 0,1 -> L0,L1; full drain.
  LOADS(rA0a, rA0b, rB0a, rB0b, 0);
  LOADS(rA1a, rA1b, rB1a, rB1b, 1);
  LOADS(rA2a, rA2b, rB2a, rB2b, 2);
  WRITES(rA0a, rA0b, rB0a, rB0b, 0);
  WRITES(rA1a, rA1b, rB1a, rB1b, 1);
  END0();

#pragma unroll 1
  for (int g = 0; g < (NKT - 6) / 3; ++g) {
    int kb = 3 * g;
    COMPUTE(0); WRITES(rA2a, rA2b, rB2a, rB2b, 2); LOADS(rA0a, rA0b, rB0a, rB0b, kb + 3); END4();
    COMPUTE(1); WRITES(rA0a, rA0b, rB0a, rB0b, 0); LOADS(rA1a, rA1b, rB1a, rB1b, kb + 4); END4();
    COMPUTE(2); WRITES(rA1a, rA1b, rB1a, rB1b, 1); LOADS(rA2a, rA2b, rB2a, rB2b, kb + 5); END4();
  }
  // tail: t = NKT-6 .. NKT-1
  COMPUTE(0); WRITES(rA2a, rA2b, rB2a, rB2b, 2); LOADS(rA0a, rA0b, rB0a, rB0b, NKT - 3); END4();
  COMPUTE(1); WRITES(rA0a, rA0b, rB0a, rB0b, 0); LOADS(rA1a, rA1b, rB1a, rB1b, NKT - 2); END4();
  COMPUTE(2); WRITES(rA1a, rA1b, rB1a, rB1b, 1); LOADS(rA2a, rA2b, rB2a, rB2b, NKT - 1); END4();
  COMPUTE(0); WRITES(rA2a, rA2b, rB2a, rB2b, 2); END4();   // writes tile NKT-1
  COMPUTE(1); END0();                                      // drain all writes
  COMPUTE(2);                                              // last tile

#undef END0
#undef END4
#undef COMPUTE
#undef WRITES
#undef LOADS

  int colbase = ct * 128 + wc;
#pragma unroll
  for (int m = 0; m < 4; m++) {
#pragma unroll
    for (int j = 0; j < 4; j++) {
      int rloc = rt * 128 + wr + m * 16 + ((lane >> 4) << 2) + j;
      if (rloc < ne) {
        if (EPI == 0) {
          size_t hrow = (size_t)(base + rloc) * NDIM;
#pragma unroll
          for (int n = 0; n < 4; n++)
            hout[hrow + colbase + n * 16 + (lane & 15)] = f2bf(gelu_f(acc[m][n][j]));
        } else {
          int t = tok[e * T_TOK + rloc];
          float w = wgt[e * T_TOK + rloc];
          float* orow = fout + (size_t)t * NDIM + colbase + (lane & 15);
#pragma unroll
          for (int n = 0; n < 4; n++)
            atomicAdd(orow + n * 16, w * acc[m][n][j]);
        }
      }
    }
  }
}

extern "C" void kernel_launch(void* const* d_in, const int* in_sizes, int n_in,
                              void* d_out, int out_size, void* d_ws, size_t ws_size,
                              hipStream_t stream) {
  const float* x   = (const float*)d_in[0];
  const float* gw  = (const float*)d_in[1];
  const float* wfc = (const float*)d_in[2];
  const float* wpj = (const float*)d_in[3];
  float* out = (float*)d_out;

  char* ws = (char*)d_ws;
  const size_t SZ_ASLAB = (size_t)MAXT * 24 * 4096 * 2;        // 14,155,776
  const size_t SZ_BFC   = (size_t)N_EXP * 24 * 24 * 4096 * 2;  // 37,748,736
  const size_t SZ_BPJ   = (size_t)N_EXP * 6 * 96 * 4096 * 2;   // 37,748,736
  const size_t SZ_H     = (size_t)2 * T_TOK * DFF * 2;         // 50,331,648
  short* aslab = (short*)(ws);
  short* bfc   = (short*)(ws + SZ_ASLAB);
  short* bpj   = (short*)(ws + SZ_ASLAB + SZ_BFC);
  short* h     = (short*)(ws + SZ_ASLAB + SZ_BFC + SZ_BPJ);
  char* p2     = ws + SZ_ASLAB + SZ_BFC + SZ_BPJ + SZ_H;
  int*   tok  = (int*)(p2);
  float* wgt  = (float*)(p2 + (size_t)N_EXP * T_TOK * 4);
  char* p3    = p2 + (size_t)N_EXP * T_TOK * 8;
  int*   cnt  = (int*)(p3);                     // padded: N_EXP*CNTS ints

  int n4 = out_size / 4;
  // fused: both weight slabs + out-zero + cnt-zero in ONE launch
  prep_kernel<<<2 * 4608, 256, 0, stream>>>(wfc, bfc, wpj, bpj, (float4*)out, n4, cnt);
  gate_kernel<<<T_TOK / 16, 256, 0, stream>>>(x, gw, cnt, tok, wgt);
  gatherA_kernel<<<dim3(MAXT, 24), 256, 0, stream>>>(x, tok, cnt, aslab);
  // FC: 3-buffer deferred-drain pipe, A=slab. K=768 (NKT=24). grid = 1728 (%8==0)
  pipe_gemm<D_EMB, DFF, 1, 8, 8, 0><<<MAXT * (DFF / 128), 256, 0, stream>>>(
      aslab, bfc, tok, wgt, cnt, h, nullptr);
  // PROJ: same, A=h rows. K=3072 split 2 (NKT=48). grid = 864 (%8==0)
  pipe_gemm<DFF, D_EMB, 2, 8, 6, 1><<<2 * MAXT * (D_EMB / 128), 256, 0, stream>>>(
      h, bpj, tok, wgt, cnt, nullptr, out);
}